// Round 1
// 2584.975 us; speedup vs baseline: 1.4210x; 1.4210x over previous
//
#include <hip/hip_runtime.h>

typedef unsigned short us_t;
typedef unsigned int u32;
typedef unsigned long long u64;
typedef __attribute__((ext_vector_type(8))) short bf16x8;
typedef __attribute__((ext_vector_type(4))) float f32x4;

// Problem constants
constexpr int V = 4000, E = 512, H = 512, NB = 32, To = 128, Ti = 512;
constexpr int T_STEPS = 129;          // To + 1

// ws layout (float offsets) — identical footprint to previous version
constexpr size_t OFF_XPRE = 0;                                   // f [129][2048][32] (transposed)
constexpr size_t OFF_WQ   = OFF_XPRE + (size_t)129*32*2048;      // us [256 b][128 r][16 col][8] packed B tiles
constexpr size_t OFF_H0B  = OFF_WQ + (size_t)256*128*16*8/2;     // us [130][64 g8][32 n][8] granule-major
constexpr size_t OFF_H1B  = OFF_H0B + (size_t)130*16384/2;       // us [130][64][32][8]
constexpr size_t OFF_H1T  = OFF_H1B + (size_t)130*16384/2;       // us [130][32][520] transposed h1 for attn
constexpr size_t OFF_ATB  = OFF_H1T + (size_t)130*16640/2;       // us [130][64][32][8] bf16 attc (granule-major)
constexpr size_t OFF_CTX  = OFF_ATB + (size_t)130*16384/2;       // f [130][64][32][8] atomic acc (normalized)
constexpr size_t OFF_MZ   = OFF_CTX + (size_t)130*16384;         // u64 [130][256]
constexpr size_t OFF_HID  = OFF_MZ + (size_t)130*256*2;          // us [4128][512] bf16 hidden
constexpr size_t OFF_W2P  = OFF_HID + (size_t)4128*512;          // us [64][4096][8] packed W2
constexpr size_t OFF_CPM  = OFF_W2P + (size_t)64*4096*8/2;       // f [4128][16]
constexpr size_t OFF_CPS  = OFF_CPM + (size_t)4128*16;
constexpr size_t OFF_TGT  = OFF_CPS + (size_t)4128*16;           // f [4128]
constexpr size_t OFF_FLG  = OFF_TGT + 4128;                      // u32 [256] dense flags

__device__ __forceinline__ float sigmf(float x) { return 1.0f / (1.0f + __expf(-x)); }
__device__ __forceinline__ float bfl(u32 u) { return __uint_as_float(u << 16); }
__device__ __forceinline__ float bfh(u32 u) { return __uint_as_float(u & 0xffff0000u); }
__device__ __forceinline__ us_t f2b(float x) {
    u32 u = __float_as_uint(x);
    return (us_t)((u + 0x7fffu + ((u >> 16) & 1u)) >> 16);
}

// ---- grid sync: dense per-block epoch flags (unchanged protocol) ----
__device__ __forceinline__ void arrive(u32* flg, int b, int tid, u32 val) {
    __syncthreads();
    if (tid == 0)
        __hip_atomic_store(flg + b, val, __ATOMIC_RELAXED, __HIP_MEMORY_SCOPE_AGENT);
}
__device__ __forceinline__ void wait_all(u32* flg, u32 target, int tid) {
    if (tid < 128) {
        const u64* f8 = (const u64*)flg;
        bool done = false;
        for (;;) {
            if (!done) {
                u64 v = __hip_atomic_load(f8 + tid, __ATOMIC_RELAXED, __HIP_MEMORY_SCOPE_AGENT);
                done = ((u32)v >= target) && ((u32)(v >> 32) >= target);
            }
            if (__all((int)done)) break;
            __builtin_amdgcn_s_sleep(2);
        }
    }
    __syncthreads();
}

// ---------------- init ----------------
__global__ __launch_bounds__(256) void k_init(float* ws) {
    int t0 = blockIdx.x * 256 + threadIdx.x;
    int nth = gridDim.x * 256;
    float4 z4 = {0.f, 0.f, 0.f, 0.f};
    float4* c4 = (float4*)(ws + OFF_CTX);
    for (int i = t0; i < 130 * 32 * 128; i += nth) c4[i] = z4;
    float4* m4 = (float4*)(ws + OFF_MZ);
    for (int i = t0; i < 130 * 128; i += nth) m4[i] = z4;
    float4* h04 = (float4*)(ws + OFF_H0B);
    float4* h14 = (float4*)(ws + OFF_H1B);
    for (int i = t0; i < 2048; i += nth) { h04[i] = z4; h14[i] = z4; }
    u32* fl = (u32*)(ws + OFF_FLG);
    if (t0 < 256) fl[t0] = 0u;
}

// ---------------- weight pre-pack for MFMA B operand ----------------
// Wq[b][r][col][j] (r=ktile*4+quad, 0..127; j=0..7): k = r*8+j (0..1023).
// cols 0..7  -> LSTM0 rows: gRow=(cl>>1)*512 + b*2 + (cl&1); k<512: W_ih0[gRow][512+k] (attc), else W_hh0[gRow][k-512]
// cols 8..15 -> LSTM1 rows: same gRow map;                  k<512: W_ih1[gRow][k] (h0), else W_hh1[gRow][k-512]
__global__ __launch_bounds__(256) void k_packWq(const float* __restrict__ W_ih0,
                                                const float* __restrict__ W_hh0,
                                                const float* __restrict__ W_ih1,
                                                const float* __restrict__ W_hh1,
                                                us_t* __restrict__ Wq) {
    int p = blockIdx.x * 256 + threadIdx.x;        // 0..4194303
    int j = p & 7, col = (p >> 3) & 15, r = (p >> 7) & 127, b = p >> 14;
    int k = r * 8 + j;
    int cl = col & 7;
    int gRow = (cl >> 1) * 512 + b * 2 + (cl & 1);
    float v;
    if (col < 8)
        v = (k < 512) ? W_ih0[(size_t)gRow * 1024 + 512 + k]
                      : W_hh0[(size_t)gRow * 512 + (k - 512)];
    else
        v = (k < 512) ? W_ih1[(size_t)gRow * 512 + k]
                      : W_hh1[(size_t)gRow * 512 + (k - 512)];
    Wq[p] = f2b(v);
}

// ---------------- W2 pre-pack (unchanged) ----------------
__global__ __launch_bounds__(256) void k_packW2(const float* __restrict__ W2,
                                                us_t* __restrict__ W2p) {
    int p = blockIdx.x * 256 + threadIdx.x;
    int j = p & 7, v = (p >> 3) & 4095, kb = p >> 15;
    float x = (v < V) ? W2[(size_t)v * 512 + kb * 8 + j] : 0.0f;
    W2p[p] = f2b(x);
}

// ---------------- X_pre GEMM (unchanged, f32) ----------------
__global__ __launch_bounds__(256) void k_xpre(const int* __restrict__ padded,
                                              const float* __restrict__ embedding,
                                              const float* __restrict__ W_ih0,
                                              const float* __restrict__ b_ih0,
                                              const float* __restrict__ b_hh0,
                                              float* __restrict__ Xpre) {
    __shared__ __align__(16) float At[32 * 33];
    __shared__ __align__(16) float Bt[32 * 68];
    __shared__ int toks[32];
    const int t = blockIdx.x, j0 = blockIdx.y * 64, tid = threadIdx.x;
    if (tid < 32) toks[tid] = (t == 0) ? 1 : padded[tid * 128 + (t - 1)];
    __syncthreads();
    const int ty = tid >> 4, tx = tid & 15;
    float acc[8];
#pragma unroll
    for (int i = 0; i < 8; ++i) acc[i] = 0.0f;
    for (int k0 = 0; k0 < 512; k0 += 32) {
        __syncthreads();
        {
            int r = tid >> 3, kk4 = tid & 7;
            float4 v = *(const float4*)(embedding + (size_t)toks[r] * 512 + k0 + kk4 * 4);
            At[(kk4 * 4 + 0) * 33 + r] = v.x;
            At[(kk4 * 4 + 1) * 33 + r] = v.y;
            At[(kk4 * 4 + 2) * 33 + r] = v.z;
            At[(kk4 * 4 + 3) * 33 + r] = v.w;
#pragma unroll
            for (int i2 = 0; i2 < 2; ++i2) {
                int f = tid + 256 * i2;
                int j = f >> 3, kb = f & 7;
                float4 w = *(const float4*)(W_ih0 + (size_t)(j0 + j) * 1024 + k0 + kb * 4);
                Bt[(kb * 4 + 0) * 68 + j] = w.x;
                Bt[(kb * 4 + 1) * 68 + j] = w.y;
                Bt[(kb * 4 + 2) * 68 + j] = w.z;
                Bt[(kb * 4 + 3) * 68 + j] = w.w;
            }
        }
        __syncthreads();
#pragma unroll
        for (int kk = 0; kk < 32; ++kk) {
            float a0 = At[kk * 33 + ty], a1 = At[kk * 33 + ty + 16];
            float4 b4 = *(const float4*)&Bt[kk * 68 + tx * 4];
            acc[0] += a0 * b4.x; acc[1] += a0 * b4.y; acc[2] += a0 * b4.z; acc[3] += a0 * b4.w;
            acc[4] += a1 * b4.x; acc[5] += a1 * b4.y; acc[6] += a1 * b4.z; acc[7] += a1 * b4.w;
        }
    }
    int j = j0 + tx * 4;
    float bi[4] = {b_ih0[j], b_ih0[j + 1], b_ih0[j + 2], b_ih0[j + 3]};
    float bh[4] = {b_hh0[j], b_hh0[j + 1], b_hh0[j + 2], b_hh0[j + 3]};
    float* base = Xpre + (size_t)t * 65536;
#pragma unroll
    for (int c = 0; c < 4; ++c) {
        base[(size_t)(j + c) * 32 + ty]      = acc[c]     + bi[c] + bh[c];
        base[(size_t)(j + c) * 32 + ty + 16] = acc[4 + c] + bi[c] + bh[c];
    }
}

// ---------------- MFMA helpers for k_seq ----------------
// A operand: lane l holds X[n = Mt*16 + (l&15)][k = 32*ktile + (l>>4)*8 + j]
// buffer layout: Ax[slot = g8*32 + n][8] bf16 (16B granules, linear)
__device__ __forceinline__ void compute4(f32x4& a0, f32x4& a1,
                                         const us_t* __restrict__ Ab, int ktbase,
                                         int Mt, int kh, int l16, int quad,
                                         const us_t* __restrict__ lw) {
#pragma unroll
    for (int i = 0; i < 4; ++i) {
        int lt = kh * 4 + i;
        bf16x8 av = *(const bf16x8*)(Ab + ((size_t)(lt * 4 + quad) * 32 + Mt * 16 + l16) * 8);
        bf16x8 bv = *(const bf16x8*)(lw + (((size_t)(ktbase + lt) * 4 + quad) * 16 + l16) * 8);
        if (i & 1) a1 = __builtin_amdgcn_mfma_f32_16x16x32_bf16(av, bv, a1, 0, 0, 0);
        else       a0 = __builtin_amdgcn_mfma_f32_16x16x32_bf16(av, bv, a0, 0, 0, 0);
    }
}

__device__ __forceinline__ void stage16(us_t* __restrict__ dst, const us_t* __restrict__ src, int tid) {
    const uint4* s = (const uint4*)src;
    uint4* d = (uint4*)dst;
#pragma unroll
    for (int i = 0; i < 4; ++i) d[tid + i * 256] = s[tid + i * 256];
}

// ctx (f32, granule-major) -> bf16 LDS granules; owner block mirrors its 8 granules to atb
__device__ __forceinline__ void stage_ctx4(us_t* __restrict__ dst, const float* __restrict__ src,
                                           us_t* __restrict__ atbt, int b, int sbase, int tid) {
#pragma unroll
    for (int i = 0; i < 4; ++i) {
        int f = tid + i * 256;
        const float* s = src + (size_t)(sbase + f) * 8;
        float4 a = *(const float4*)s;
        float4 c = *(const float4*)(s + 4);
        u32 w0, w1, w2, w3;
        asm("v_cvt_pk_bf16_f32 %0, %1, %2" : "=v"(w0) : "v"(a.x), "v"(a.y));
        asm("v_cvt_pk_bf16_f32 %0, %1, %2" : "=v"(w1) : "v"(a.z), "v"(a.w));
        asm("v_cvt_pk_bf16_f32 %0, %1, %2" : "=v"(w2) : "v"(c.x), "v"(c.y));
        asm("v_cvt_pk_bf16_f32 %0, %1, %2" : "=v"(w3) : "v"(c.z), "v"(c.w));
        uint4 pk = {w0, w1, w2, w3};
        *(uint4*)(dst + (size_t)f * 8) = pk;
        int gs = sbase + f;
        if ((gs >> 3) == b) *(uint4*)(atbt + (size_t)gs * 8) = pk;
    }
}

// ---------------- gate reduction + nonlinearity + publish (MFMA tail) ----------------
__device__ __forceinline__ void tail_pub(f32x4 acc, int colbase,
                                         float g0, float g1, float g2, float g3,
                                         float& creg, u32* __restrict__ hOut32,
                                         u32* __restrict__ hT32,
                                         int b, int tid, float* red, float* gv) {
    const int l16 = tid & 15, quad = (tid >> 4) & 3, w = tid >> 6;
    const int Mt = w & 1, kh = w >> 1;
    const int cl = l16 - colbase;
    __syncthreads();
    if (kh == 1 && (unsigned)cl < 8u) {
        float4 v = {acc[0], acc[1], acc[2], acc[3]};
        *(float4*)&red[((size_t)(Mt * 8 + cl)) * 24 + quad * 4] = v;
    }
    __syncthreads();
    if (kh == 0 && (unsigned)cl < 8u) {
        float4 v = *(const float4*)&red[((size_t)(Mt * 8 + cl)) * 24 + quad * 4];
        float* g = gv + cl * 33 + Mt * 16 + quad * 4;
        g[0] = acc[0] + v.x; g[1] = acc[1] + v.y; g[2] = acc[2] + v.z; g[3] = acc[3] + v.w;
    }
    __syncthreads();
    if (tid < 64) {
        int jl = tid >> 5, n = tid & 31;
        float gi = gv[jl * 33 + n]       + g0;
        float gf = gv[(2 + jl) * 33 + n] + g1;
        float gg = gv[(4 + jl) * 33 + n] + g2;
        float go = gv[(6 + jl) * 33 + n] + g3;
        float cn = sigmf(gf) * creg + sigmf(gi) * tanhf(gg);
        float hn = sigmf(go) * tanhf(cn);
        creg = cn;
        float hO = __shfl_xor(hn, 32);             // partner unit (jl^1), same sample
        if (jl == 0) {
            u32 pk = (u32)f2b(hn) | ((u32)f2b(hO) << 16);
            // granule-major publish: unit 2b,2b+1 -> granule b>>2, u32 sub-slot b&3
            __hip_atomic_store(hOut32 + (((size_t)(b >> 2) * 32 + n) * 4 + (b & 3)), pk,
                               __ATOMIC_RELAXED, __HIP_MEMORY_SCOPE_AGENT);
            if (hT32)
                __hip_atomic_store(hT32 + (n * 260 + b), pk,
                                   __ATOMIC_RELAXED, __HIP_MEMORY_SCOPE_AGENT);
        }
    }
}

// ---------------- cooperative sequential kernel ----------------
__global__ __launch_bounds__(256, 1) void k_seq(float* ws,
                                                const float* __restrict__ enc,
                                                const float* __restrict__ b_ih1,
                                                const float* __restrict__ b_hh1) {
    __shared__ __align__(16) us_t lds_w[16384];      // 32 KB: Wq slice [128 r][16 col][8]
    __shared__ __align__(16) us_t lds_e[64 * 552];   // 69 KB enc slice bf16, skewed
    __shared__ __align__(16) us_t Ax[2][8192];       // 2 x 16 KB X granule buffers (K=256 each)
    __shared__ __align__(16) float red_s[16 * 24];   // cross-wave K-reduce
    __shared__ __align__(16) float gv_s[272];

    const int b = blockIdx.x, tid = threadIdx.x;
    const int w = tid >> 6, l16 = tid & 15, quad = (tid >> 4) & 3;
    const int Mt = w & 1, kh = w >> 1;
    us_t* Ax0 = Ax[0];
    us_t* Ax1 = Ax[1];

    float* Xpre = ws + OFF_XPRE;
    us_t* h0b = (us_t*)(ws + OFF_H0B);
    us_t* h1b = (us_t*)(ws + OFF_H1B);
    u32*  h1T32 = (u32*)(ws + OFF_H1T);
    us_t* atb = (us_t*)(ws + OFF_ATB);
    float* ctx = ws + OFF_CTX;
    u64*  mz  = (u64*)(ws + OFF_MZ);
    u32* flg = (u32*)(ws + OFF_FLG);

    float c0r = 0.0f, c1r = 0.0f;

    // hoisted P2 bias sums (constant across t)
    float bs0 = 0.f, bs1 = 0.f, bs2 = 0.f, bs3 = 0.f;
    if (tid < 64) {
        int j = b * 2 + (tid >> 5);
        bs0 = b_ih1[j] + b_hh1[j];
        bs1 = b_ih1[512 + j] + b_hh1[512 + j];
        bs2 = b_ih1[1024 + j] + b_hh1[1024 + j];
        bs3 = b_ih1[1536 + j] + b_hh1[1536 + j];
    }

    // ---- one-time LDS residency: weights + enc slice ----
    {
        const uint4* wsrc = (const uint4*)((const us_t*)(ws + OFF_WQ) + (size_t)b * 16384);
        for (int f = tid; f < 2048; f += 256) ((uint4*)lds_w)[f] = wsrc[f];
        const int n = b >> 3, ts0 = (b & 7) * 64;
        const float4* encn = (const float4*)(enc + ((size_t)n * 512 + ts0) * 512);
#pragma unroll 4
        for (int j = 0; j < 32; ++j) {
            int f = tid + j * 256;
            int row = f >> 7, c4 = f & 127;
            float4 v = encn[(size_t)row * 128 + c4];
            ushort4 o;
            o.x = f2b(v.x); o.y = f2b(v.y); o.z = f2b(v.z); o.w = f2b(v.w);
            *(ushort4*)(lds_e + (size_t)row * 552 + (c4 >> 5) * 136 + (c4 & 31) * 4) = o;
        }
    }
    __syncthreads();

    for (int t = 0; t < T_STEPS; ++t) {
        const u32 base = 3u * t;
        // ============ P1: LSTM0, X = [attc(t) k0..511 | h0(t) k512..1023] ============
        float xg0 = 0.f, xg1 = 0.f, xg2 = 0.f, xg3 = 0.f;
        if (tid < 64) {
            const float* xp = Xpre + (size_t)t * 65536;
            int j = b * 2 + (tid >> 5), nn = tid & 31;
            xg0 = xp[(size_t)(0    + j) * 32 + nn];
            xg1 = xp[(size_t)(512  + j) * 32 + nn];
            xg2 = xp[(size_t)(1024 + j) * 32 + nn];
            xg3 = xp[(size_t)(1536 + j) * 32 + nn];
        }
        f32x4 acc, accB;
#pragma unroll
        for (int r = 0; r < 4; ++r) { acc[r] = 0.0f; accB[r] = 0.0f; }
        {   // h0(t) half first (no barrier dependency): ktiles 16..31
            const us_t* h0s = h0b + (size_t)t * 16384;
            stage16(Ax0, h0s, tid);
            __syncthreads();
            uint4 r0, r1, r2, r3;
            {
                const uint4* s = (const uint4*)(h0s + 8192);
                r0 = s[tid]; r1 = s[tid + 256]; r2 = s[tid + 512]; r3 = s[tid + 768];
            }
            compute4(acc, accB, Ax0, 16, Mt, kh, l16, quad, lds_w);
            {
                uint4* d = (uint4*)Ax1;
                d[tid] = r0; d[tid + 256] = r1; d[tid + 512] = r2; d[tid + 768] = r3;
            }
            __syncthreads();
            compute4(acc, accB, Ax1, 24, Mt, kh, l16, quad, lds_w);
        }
        wait_all(flg, base, tid);                  // attc(t) (normalized) ready
        {
            const float* cts = ctx + (size_t)t * 16384;
            us_t* atbt = atb + (size_t)t * 16384;
            stage_ctx4(Ax0, cts, atbt, b, 0, tid);
            __syncthreads();
            // prefetch S3 (slots 1024..2047) while computing S2
            float4 pa[4], pc[4];
#pragma unroll
            for (int i = 0; i < 4; ++i) {
                const float* s = cts + (size_t)(1024 + tid + i * 256) * 8;
                pa[i] = *(const float4*)s;
                pc[i] = *(const float4*)(s + 4);
            }
            compute4(acc, accB, Ax0, 0, Mt, kh, l16, quad, lds_w);
#pragma unroll
            for (int i = 0; i < 4; ++i) {
                int f = tid + i * 256;
                u32 w0, w1, w2, w3;
                asm("v_cvt_pk_bf16_f32 %0, %1, %2" : "=v"(w0) : "v"(pa[i].x), "v"(pa[i].y));
                asm("v_cvt_pk_bf16_f32 %0, %1, %2" : "=v"(w1) : "v"(pa[i].z), "v"(pa[i].w));
                asm("v_cvt_pk_bf16_f32 %0, %1, %2" : "=v"(w2) : "v"(pc[i].x), "v"(pc[i].y));
                asm("v_cvt_pk_bf16_f32 %0, %1, %2" : "=v"(w3) : "v"(pc[i].z), "v"(pc[i].w));
                uint4 pk = {w0, w1, w2, w3};
                *(uint4*)(Ax1 + (size_t)f * 8) = pk;
                int gs = 1024 + f;
                if ((gs >> 3) == b) *(uint4*)(atbt + (size_t)gs * 8) = pk;
            }
            __syncthreads();
            compute4(acc, accB, Ax1, 8, Mt, kh, l16, quad, lds_w);
        }
        {
            f32x4 aS = acc + accB;
            tail_pub(aS, 0, xg0, xg1, xg2, xg3, c0r,
                     (u32*)(h0b + (size_t)(t + 1) * 16384), nullptr, b, tid, red_s, gv_s);
        }
        arrive(flg, b, tid, base + 1);
        // ============ P2: LSTM1, X = [h0(t+1) k0..511 | h1(t) k512..1023] ============
#pragma unroll
        for (int r = 0; r < 4; ++r) { acc[r] = 0.0f; accB[r] = 0.0f; }
        {   // h1(t) half first: ktiles 16..31
            const us_t* h1s = h1b + (size_t)t * 16384;
            stage16(Ax0, h1s, tid);
            __syncthreads();
            uint4 r0, r1, r2, r3;
            {
                const uint4* s = (const uint4*)(h1s + 8192);
                r0 = s[tid]; r1 = s[tid + 256]; r2 = s[tid + 512]; r3 = s[tid + 768];
            }
            compute4(acc, accB, Ax0, 16, Mt, kh, l16, quad, lds_w);
            {
                uint4* d = (uint4*)Ax1;
                d[tid] = r0; d[tid + 256] = r1; d[tid + 512] = r2; d[tid + 768] = r3;
            }
            __syncthreads();
            compute4(acc, accB, Ax1, 24, Mt, kh, l16, quad, lds_w);
        }
        wait_all(flg, base + 1, tid);
        {
            const us_t* h0n = h0b + (size_t)(t + 1) * 16384;
            stage16(Ax0, h0n, tid);
            __syncthreads();
            uint4 r0, r1, r2, r3;
            {
                const uint4* s = (const uint4*)(h0n + 8192);
                r0 = s[tid]; r1 = s[tid + 256]; r2 = s[tid + 512]; r3 = s[tid + 768];
            }
            compute4(acc, accB, Ax0, 0, Mt, kh, l16, quad, lds_w);
            {
                uint4* d = (uint4*)Ax1;
                d[tid] = r0; d[tid + 256] = r1; d[tid + 512] = r2; d[tid + 768] = r3;
            }
            __syncthreads();
            compute4(acc, accB, Ax1, 8, Mt, kh, l16, quad, lds_w);
        }
        {
            f32x4 aS = acc + accB;
            tail_pub(aS, 8, bs0, bs1, bs2, bs3, c1r,
                     (u32*)(h1b + (size_t)(t + 1) * 16384),
                     h1T32 + (size_t)(t + 1) * 8320, b, tid, red_s, gv_s);
        }
        arrive(flg, b, tid, base + 2);
        // ============ ATTN: single-pass, 8 blocks/sample, mini-sync + normalized atomic ctx ============
        wait_all(flg, base + 2, tid);
        {
            const int n = b >> 3, c = b & 7;
            float* h_l = (float*)Ax0;  // 512
            float* scp = h_l + 512;    // 256
            float* p_l = h_l + 768;    // 64
            {
                u32 hv = h1T32[(size_t)(t + 1) * 8320 + n * 260 + tid];
                float2 h2 = {bfl(hv), bfh(hv)};
                *(float2*)(h_l + tid * 2) = h2;
            }
            __syncthreads();
            {
                int ti = tid >> 2, kp = tid & 3;
                const us_t* er = lds_e + (size_t)ti * 552 + kp * 136;
                const float* hr = h_l + kp * 128;
                float s = 0.0f;
#pragma unroll
                for (int k8 = 0; k8 < 16; ++k8) {
                    uint4 u = *(const uint4*)(er + k8 * 8);
                    const float* h8 = hr + k8 * 8;
                    s += bfl(u.x) * h8[0] + bfh(u.x) * h8[1]
                       + bfl(u.y) * h8[2] + bfh(u.y) * h8[3]
                       + bfl(u.z) * h8[4] + bfh(u.z) * h8[5]
                       + bfl(u.w) * h8[6] + bfh(u.w) * h8[7];
                }
                scp[kp * 64 + ti] = s;
            }
            __syncthreads();
            if (tid < 64) {
                float sc = scp[tid] + scp[64 + tid] + scp[128 + tid] + scp[192 + tid];
                float m = sc;
                for (int o = 32; o; o >>= 1) m = fmaxf(m, __shfl_xor(m, o));
                float e = __expf(sc - m);
                float z = e;
                for (int o = 32; o; o >>= 1) z += __shfl_xor(z, o);
                p_l[tid] = e;
                if (tid == 0) {
                    h_l[840] = m;      // own chunk max
                    u64 pk = ((u64)__float_as_uint(m) << 32) | (u64)__float_as_uint(z);
                    __hip_atomic_store(mz + ((size_t)(t + 1) * 256 + n * 8 + c), pk,
                                       __ATOMIC_RELAXED, __HIP_MEMORY_SCOPE_AGENT);
                }
            }
            // mini-sync among the 8 chunk blocks of this sample -> global (M, Z)
            if (tid < 8) {
                u64 v;
                for (;;) {
                    v = __hip_atomic_load(mz + ((size_t)(t + 1) * 256 + n * 8 + tid),
                                          __ATOMIC_RELAXED, __HIP_MEMORY_SCOPE_AGENT);
                    if ((u32)v != 0u) break;
                    __builtin_amdgcn_s_sleep(1);
                }
                float mi = __uint_as_float((u32)(v >> 32));
                float zi = __uint_as_float((u32)v);
#pragma unroll
                for (int o = 1; o < 8; o <<= 1) {
                    float mo = __shfl_xor(mi, o);
                    float zo = __shfl_xor(zi, o);
                    float Mn = fmaxf(mi, mo);
                    zi = zi * __expf(mi - Mn) + zo * __expf(mo - Mn);
                    mi = Mn;
                }
                if (tid == 0)
                    h_l[841] = __expf(h_l[840] - mi) / zi;   // normalized scale for this chunk
            }
            __syncthreads();
            float scl = h_l[841];
            {
                int f0 = tid * 2;
                const us_t* eb = lds_e + (f0 >> 7) * 136 + (f0 & 127);
                float cv0 = 0.0f, cv1 = 0.0f;
#pragma unroll 8
                for (int ti = 0; ti < 64; ++ti) {
                    float wgt = p_l[ti];
                    u32 u = *(const u32*)(eb + (size_t)ti * 552);
                    cv0 += wgt * bfl(u); cv1 += wgt * bfh(u);
                }
                // granule-major ctx: slot = (dim>>3)*32 + n, element dim&7
                int gs = (f0 >> 3) * 32 + n;
                float* dst = ctx + (size_t)(t + 1) * 16384 + (size_t)gs * 8 + (f0 & 7);
                __hip_atomic_fetch_add(dst,     cv0 * scl, __ATOMIC_RELAXED, __HIP_MEMORY_SCOPE_AGENT);
                __hip_atomic_fetch_add(dst + 1, cv1 * scl, __ATOMIC_RELAXED, __HIP_MEMORY_SCOPE_AGENT);
            }
        }
        arrive(flg, b, tid, base + 3);
    }
    // tail: materialize bf16 attc(129) for k_mlp (ctx already normalized)
    wait_all(flg, 3u * T_STEPS, tid);
    if (tid < 8) {
        int gs = b * 8 + tid;
        const float* s = ctx + (size_t)129 * 16384 + (size_t)gs * 8;
        float4 a = *(const float4*)s;
        float4 c = *(const float4*)(s + 4);
        u32 w0, w1, w2, w3;
        asm("v_cvt_pk_bf16_f32 %0, %1, %2" : "=v"(w0) : "v"(a.x), "v"(a.y));
        asm("v_cvt_pk_bf16_f32 %0, %1, %2" : "=v"(w1) : "v"(a.z), "v"(a.w));
        asm("v_cvt_pk_bf16_f32 %0, %1, %2" : "=v"(w2) : "v"(c.x), "v"(c.y));
        asm("v_cvt_pk_bf16_f32 %0, %1, %2" : "=v"(w3) : "v"(c.z), "v"(c.w));
        uint4 pk = {w0, w1, w2, w3};
        *(uint4*)(atb + (size_t)129 * 16384 + (size_t)gs * 8) = pk;
    }
}

// ---------------- MLP hidden GEMM (granule-major bf16 in, bf16 out) ----------------
__global__ __launch_bounds__(256) void k_mlp(const us_t* __restrict__ h1b,
                                             const us_t* __restrict__ atb,
                                             const float* __restrict__ W1,
                                             const float* __restrict__ b1,
                                             us_t* __restrict__ hidb) {
    __shared__ __align__(16) float At[32 * 33];
    __shared__ __align__(16) float Bt[32 * 68];
    const int t = blockIdx.x, j0 = blockIdx.y * 64, tid = threadIdx.x;
    const int ty = tid >> 4, tx = tid & 15;
    float acc[8];
#pragma unroll
    for (int i = 0; i < 8; ++i) acc[i] = 0.0f;
    for (int k0 = 0; k0 < 1024; k0 += 32) {
        const us_t* src = (k0 < 512) ? (h1b + (size_t)(t + 1) * 16384 + (size_t)k0 * 32)
                                     : (atb + (size_t)t * 16384 + (size_t)(k0 - 512) * 32);
        __syncthreads();
        if (tid < 128) {   // 32k x 32n tile = 4 granule-rows
            int g8l = tid >> 5, n = tid & 31;
            uint4 v = *(const uint4*)(src + ((size_t)g8l * 32 + n) * 8);
            float* a = At + (size_t)(g8l * 8) * 33 + n;
            a[0]   = bfl(v.x); a[33]  = bfh(v.x);
            a[66]  = bfl(v.y); a[99]  = bfh(v.y);
            a[132] = bfl(v.z); a[165] = bfh(v.z);
            a[198] = bfl(v.w); a[231] = bfh(v.w);
        }
        {
#pragma unroll
            for (int i2 = 0; i2 < 2; ++i2) {
                int f = tid + 256 * i2;
                int j = f >> 3, kb = f & 7;
                float4 wv = *(const float4*)(W1 + (size_t)(j0 + j) * 1024 + k0 + kb * 4);
                Bt[(kb * 4 + 0) * 68 + j] = wv.x;
                Bt[(kb * 4 + 1) * 68 + j] = wv.y;
                Bt[(kb * 4 + 2) * 68 + j] = wv.z;
                Bt[(kb * 4 + 3) * 68 + j] = wv.w;
            }
        }
        __syncthreads();
#pragma unroll
        for (int kk = 0; kk < 32; ++kk) {
            float a0 = At[kk * 33 + ty], a1 = At[kk * 33 + ty + 16];
            float4 b4 = *(const float4*)&Bt[kk * 68 + tx * 4];
            acc[0] += a0 * b4.x; acc[1] += a0 * b4.y; acc[2] += a0 * b4.z; acc[3] += a0 * b4.w;
            acc[4] += a1 * b4.x; acc[5] += a1 * b4.y; acc[6] += a1 * b4.z; acc[7] += a1 * b4.w;
        }
    }
    int j = j0 + tx * 4;
    float4 bv = *(const float4*)(b1 + j);
    int r0 = t * 32;
    ushort4 p0 = {f2b(tanhf(acc[0] + bv.x)), f2b(tanhf(acc[1] + bv.y)),
                  f2b(tanhf(acc[2] + bv.z)), f2b(tanhf(acc[3] + bv.w))};
    ushort4 p1 = {f2b(tanhf(acc[4] + bv.x)), f2b(tanhf(acc[5] + bv.y)),
                  f2b(tanhf(acc[6] + bv.z)), f2b(tanhf(acc[7] + bv.w))};
    *(ushort4*)(hidb + (size_t)(r0 + ty) * 512 + j) = p0;
    *(ushort4*)(hidb + (size_t)(r0 + ty + 16) * 512 + j) = p1;
}

// ---------------- MFMA logits + chunk logsumexp (unchanged) ----------------
__global__ __launch_bounds__(256) void k_ce(const us_t* __restrict__ hidb,
                                            const us_t* __restrict__ W2p,
                                            const float* __restrict__ b2,
                                            const int* __restrict__ padded,
                                            float* __restrict__ cpm, float* __restrict__ cps,
                                            float* __restrict__ tgt) {
    __shared__ __align__(16) us_t Ash[32 * 520];
    __shared__ __align__(16) float lg[256 * 33];
    __shared__ float mred[8 * 32];
    __shared__ float Mf[32];
    __shared__ float sred[8 * 32];
    const int t = blockIdx.x, vc = blockIdx.y, tid = threadIdx.x;
    {
        const uint4* src = (const uint4*)(hidb + (size_t)t * 32 * 512);
#pragma unroll
        for (int i = 0; i < 8; ++i) {
            int f = tid + i * 256;
            uint4 v = src[f];
            *(uint4*)(Ash + (size_t)(f >> 6) * 520 + (f & 63) * 8) = v;
        }
    }
    __syncthreads();
    const int w = tid >> 6, lane = tid & 63;
    const int quad = lane >> 4, l16 = lane & 15;
    f32x4 acc[2][4];
#pragma unroll
    for (int mt = 0; mt < 2; ++mt)
#pragma unroll
        for (int nt = 0; nt < 4; ++nt)
#pragma unroll
            for (int r = 0; r < 4; ++r) acc[mt][nt][r] = 0.0f;
    const int vbase = vc * 256 + w * 64;
    for (int ks = 0; ks < 16; ++ks) {
        bf16x8 a0 = *(const bf16x8*)(Ash + (size_t)(l16)      * 520 + ks * 32 + quad * 8);
        bf16x8 a1 = *(const bf16x8*)(Ash + (size_t)(16 + l16) * 520 + ks * 32 + quad * 8);
        const us_t* bp = W2p + ((size_t)(ks * 4 + quad) * 4096 + vbase + l16) * 8;
#pragma unroll
        for (int nt = 0; nt < 4; ++nt) {
            bf16x8 bb = *(const bf16x8*)(bp + nt * 128);
            acc[0][nt] = __builtin_amdgcn_mfma_f32_16x16x32_bf16(a0, bb, acc[0][nt], 0, 0, 0);
            acc[1][nt] = __builtin_amdgcn_mfma_f32_16x16x32_bf16(a1, bb, acc[1][nt], 0, 0, 0);
        }
    }
#pragma unroll
    for (int nt = 0; nt < 4; ++nt) {
        int vloc = w * 64 + nt * 16 + l16;
        int vglob = vc * 256 + vloc;
        float bias = (vglob < V) ? b2[vglob] : -1e30f;
#pragma unroll
        for (int mt = 0; mt < 2; ++mt)
#pragma unroll
            for (int r = 0; r < 4; ++r)
                lg[vloc * 33 + mt * 16 + quad * 4 + r] = acc[mt][nt][r] + bias;
    }
    __syncthreads();
    {
        int n = tid & 31, c = tid >> 5;
        float m = -1e30f;
        for (int i = 0; i < 32; ++i) m = fmaxf(m, lg[(c * 32 + i) * 33 + n]);
        mred[c * 32 + n] = m;
    }
    __syncthreads();
    if (tid < 32) {
        float M = mred[tid];
#pragma unroll
        for (int c = 1; c < 8; ++c) M = fmaxf(M, mred[c * 32 + tid]);
        Mf[tid] = M;
    }
    __syncthreads();
    {
        int n = tid & 31, c = tid >> 5;
        float M = Mf[n], s = 0.0f;
        for (int i = 0; i < 32; ++i) s += __expf(lg[(c * 32 + i) * 33 + n] - M);
        sred[c * 32 + n] = s;
    }
    __syncthreads();
    if (tid < 32) {
        int n = tid;
        float S = 0.0f;
#pragma unroll
        for (int c = 0; c < 8; ++c) S += sred[c * 32 + n];
        int r = t * 32 + n;
        cpm[(size_t)r * 16 + vc] = Mf[n];
        cps[(size_t)r * 16 + vc] = S;
        int vstar = (t < 128) ? padded[n * 128 + t] : 2;
        int vl = vstar - vc * 256;
        if (vl >= 0 && vl < 256) tgt[r] = lg[vl * 33 + n];
    }
}

// ---------------- final combine + CE reduction (unchanged) ----------------
__global__ __launch_bounds__(256) void k_final(const float* __restrict__ cpm,
                                               const float* __restrict__ cps,
                                               const float* __restrict__ tgt,
                                               float* __restrict__ out) {
    __shared__ float red[256];
    float local = 0.0f;
    for (int r = threadIdx.x; r < 4128; r += 256) {
        float M = -1e30f;
#pragma unroll
        for (int c = 0; c < 16; ++c) M = fmaxf(M, cpm[(size_t)r * 16 + c]);
        float S = 0.0f;
#pragma unroll
        for (int c = 0; c < 16; ++c) S += cps[(size_t)r * 16 + c] * __expf(cpm[(size_t)r * 16 + c] - M);
        local += (M + logf(S)) - tgt[r];
    }
    red[threadIdx.x] = local;
    __syncthreads();
    for (int o = 128; o; o >>= 1) {
        if (threadIdx.x < o) red[threadIdx.x] += red[threadIdx.x + o];
        __syncthreads();
    }
    if (threadIdx.x == 0) out[0] = red[0] * (128.0f / 4128.0f);
}

extern "C" void kernel_launch(void* const* d_in, const int* in_sizes, int n_in,
                              void* d_out, int out_size, void* d_ws, size_t ws_size,
                              hipStream_t stream) {
    const int*   padded = (const int*)d_in[0];
    const float* enc    = (const float*)d_in[1];
    const float* emb    = (const float*)d_in[2];
    const float* W_ih0  = (const float*)d_in[3];
    const float* b_ih0  = (const float*)d_in[4];
    const float* W_hh0  = (const float*)d_in[5];
    const float* b_hh0  = (const float*)d_in[6];
    const float* W_ih1  = (const float*)d_in[7];
    const float* b_ih1  = (const float*)d_in[8];
    const float* W_hh1  = (const float*)d_in[9];
    const float* b_hh1  = (const float*)d_in[10];
    const float* W1     = (const float*)d_in[11];
    const float* b1     = (const float*)d_in[12];
    const float* W2     = (const float*)d_in[13];
    const float* b2     = (const float*)d_in[14];
    float* ws  = (float*)d_ws;
    float* out = (float*)d_out;

    hipLaunchKernelGGL(k_init, dim3(640), dim3(256), 0, stream, ws);
    hipLaunchKernelGGL(k_packWq, dim3(16384), dim3(256), 0, stream,
                       W_ih0, W_hh0, W_ih1, W_hh1, (us_t*)(ws + OFF_WQ));
    hipLaunchKernelGGL(k_packW2, dim3(8192), dim3(256), 0, stream,
                       W2, (us_t*)(ws + OFF_W2P));
    hipLaunchKernelGGL(k_xpre, dim3(129, 32), dim3(256), 0, stream,
                       padded, emb, W_ih0, b_ih0, b_hh0, ws + OFF_XPRE);
    {
        float* ws_a = ws;
        const float* enc_a = enc;
        const float* bia = b_ih1;
        const float* bib = b_hh1;
        void* args[] = {(void*)&ws_a, (void*)&enc_a, (void*)&bia, (void*)&bib};
        hipLaunchCooperativeKernel((void*)k_seq, dim3(256), dim3(256), args, 0, stream);
    }
    hipLaunchKernelGGL(k_mlp, dim3(129, 8), dim3(256), 0, stream,
                       (const us_t*)(ws + OFF_H1B), (const us_t*)(ws + OFF_ATB), W1, b1,
                       (us_t*)(ws + OFF_HID));
    hipLaunchKernelGGL(k_ce, dim3(129, 16), dim3(256), 0, stream,
                       (const us_t*)(ws + OFF_HID), (const us_t*)(ws + OFF_W2P), b2, padded,
                       ws + OFF_CPM, ws + OFF_CPS, ws + OFF_TGT);
    hipLaunchKernelGGL(k_final, dim3(1), dim3(256), 0, stream,
                       ws + OFF_CPM, ws + OFF_CPS, ws + OFF_TGT, out);
}

// Round 2
// 2324.401 us; speedup vs baseline: 1.5803x; 1.1121x over previous
//
#include <hip/hip_runtime.h>

typedef unsigned short us_t;
typedef unsigned int u32;
typedef unsigned long long u64;
typedef __attribute__((ext_vector_type(8))) short bf16x8;
typedef __attribute__((ext_vector_type(4))) float f32x4;

// Problem constants
constexpr int V = 4000, E = 512, H = 512, NB = 32, To = 128, Ti = 512;
constexpr int T_STEPS = 129;          // To + 1

// ws layout (float offsets)
constexpr size_t OFF_XPRE = 0;                                   // f [129][2048][32] (transposed)
constexpr size_t OFF_WQ   = OFF_XPRE + (size_t)129*32*2048;      // us [256 b][128 r][16 col][8] packed B tiles
constexpr size_t OFF_H0B  = OFF_WQ + (size_t)256*128*16*8/2;     // us [130][64 g8][32 n][8] granule-major
constexpr size_t OFF_H1B  = OFF_H0B + (size_t)130*16384/2;       // us [130][64][32][8]
constexpr size_t OFF_H1T  = OFF_H1B + (size_t)130*16384/2;       // us [130][32][520] transposed h1 for attn
constexpr size_t OFF_ATB  = OFF_H1T + (size_t)130*16640/2;       // us [130][64][32][8] bf16 attc (granule-major)
constexpr size_t OFF_CTX  = OFF_ATB + (size_t)130*16384/2;       // f [130][64][32][8] atomic acc (normalized)
constexpr size_t OFF_MZ   = OFF_CTX + (size_t)130*16384;         // u64 [130][256]
constexpr size_t OFF_HID  = OFF_MZ + (size_t)130*256*2;          // us [4128][512] bf16 hidden
constexpr size_t OFF_W2P  = OFF_HID + (size_t)4128*512;          // us [64][4096][8] packed W2
constexpr size_t OFF_CPM  = OFF_W2P + (size_t)64*4096*8/2;       // f [4128][16]
constexpr size_t OFF_CPS  = OFF_CPM + (size_t)4128*16;
constexpr size_t OFF_TGT  = OFF_CPS + (size_t)4128*16;           // f [4128]
constexpr size_t OFF_FLG  = OFF_TGT + 4128;                      // u32 [256] dense flags

__device__ __forceinline__ float sigmf(float x) { return 1.0f / (1.0f + __expf(-x)); }
__device__ __forceinline__ float bfl(u32 u) { return __uint_as_float(u << 16); }
__device__ __forceinline__ float bfh(u32 u) { return __uint_as_float(u & 0xffff0000u); }
__device__ __forceinline__ us_t f2b(float x) {
    u32 u = __float_as_uint(x);
    return (us_t)((u + 0x7fffu + ((u >> 16) & 1u)) >> 16);
}

// ---- grid sync: dense per-block epoch flags (unchanged protocol) ----
__device__ __forceinline__ void arrive(u32* flg, int b, int tid, u32 val) {
    __syncthreads();
    if (tid == 0)
        __hip_atomic_store(flg + b, val, __ATOMIC_RELAXED, __HIP_MEMORY_SCOPE_AGENT);
}
__device__ __forceinline__ void wait_all(u32* flg, u32 target, int tid) {
    if (tid < 128) {
        const u64* f8 = (const u64*)flg;
        bool done = false;
        for (;;) {
            if (!done) {
                u64 v = __hip_atomic_load(f8 + tid, __ATOMIC_RELAXED, __HIP_MEMORY_SCOPE_AGENT);
                done = ((u32)v >= target) && ((u32)(v >> 32) >= target);
            }
            if (__all((int)done)) break;
            __builtin_amdgcn_s_sleep(2);
        }
    }
    __syncthreads();
}

// ---------------- init ----------------
__global__ __launch_bounds__(256) void k_init(float* ws) {
    int t0 = blockIdx.x * 256 + threadIdx.x;
    int nth = gridDim.x * 256;
    float4 z4 = {0.f, 0.f, 0.f, 0.f};
    float4* c4 = (float4*)(ws + OFF_CTX);
    for (int i = t0; i < 130 * 32 * 128; i += nth) c4[i] = z4;
    float4* m4 = (float4*)(ws + OFF_MZ);
    for (int i = t0; i < 130 * 128; i += nth) m4[i] = z4;
    float4* h04 = (float4*)(ws + OFF_H0B);
    float4* h14 = (float4*)(ws + OFF_H1B);
    for (int i = t0; i < 2048; i += nth) { h04[i] = z4; h14[i] = z4; }
    u32* fl = (u32*)(ws + OFF_FLG);
    if (t0 < 256) fl[t0] = 0u;
}

// ---------------- weight pre-pack for MFMA B operand (unchanged) ----------------
__global__ __launch_bounds__(256) void k_packWq(const float* __restrict__ W_ih0,
                                                const float* __restrict__ W_hh0,
                                                const float* __restrict__ W_ih1,
                                                const float* __restrict__ W_hh1,
                                                us_t* __restrict__ Wq) {
    int p = blockIdx.x * 256 + threadIdx.x;        // 0..4194303
    int j = p & 7, col = (p >> 3) & 15, r = (p >> 7) & 127, b = p >> 14;
    int k = r * 8 + j;
    int cl = col & 7;
    int gRow = (cl >> 1) * 512 + b * 2 + (cl & 1);
    float v;
    if (col < 8)
        v = (k < 512) ? W_ih0[(size_t)gRow * 1024 + 512 + k]
                      : W_hh0[(size_t)gRow * 512 + (k - 512)];
    else
        v = (k < 512) ? W_ih1[(size_t)gRow * 512 + k]
                      : W_hh1[(size_t)gRow * 512 + (k - 512)];
    Wq[p] = f2b(v);
}

// ---------------- W2 pre-pack (unchanged) ----------------
__global__ __launch_bounds__(256) void k_packW2(const float* __restrict__ W2,
                                                us_t* __restrict__ W2p) {
    int p = blockIdx.x * 256 + threadIdx.x;
    int j = p & 7, v = (p >> 3) & 4095, kb = p >> 15;
    float x = (v < V) ? W2[(size_t)v * 512 + kb * 8 + j] : 0.0f;
    W2p[p] = f2b(x);
}

// ---------------- X_pre GEMM (unchanged, f32) ----------------
__global__ __launch_bounds__(256) void k_xpre(const int* __restrict__ padded,
                                              const float* __restrict__ embedding,
                                              const float* __restrict__ W_ih0,
                                              const float* __restrict__ b_ih0,
                                              const float* __restrict__ b_hh0,
                                              float* __restrict__ Xpre) {
    __shared__ __align__(16) float At[32 * 33];
    __shared__ __align__(16) float Bt[32 * 68];
    __shared__ int toks[32];
    const int t = blockIdx.x, j0 = blockIdx.y * 64, tid = threadIdx.x;
    if (tid < 32) toks[tid] = (t == 0) ? 1 : padded[tid * 128 + (t - 1)];
    __syncthreads();
    const int ty = tid >> 4, tx = tid & 15;
    float acc[8];
#pragma unroll
    for (int i = 0; i < 8; ++i) acc[i] = 0.0f;
    for (int k0 = 0; k0 < 512; k0 += 32) {
        __syncthreads();
        {
            int r = tid >> 3, kk4 = tid & 7;
            float4 v = *(const float4*)(embedding + (size_t)toks[r] * 512 + k0 + kk4 * 4);
            At[(kk4 * 4 + 0) * 33 + r] = v.x;
            At[(kk4 * 4 + 1) * 33 + r] = v.y;
            At[(kk4 * 4 + 2) * 33 + r] = v.z;
            At[(kk4 * 4 + 3) * 33 + r] = v.w;
#pragma unroll
            for (int i2 = 0; i2 < 2; ++i2) {
                int f = tid + 256 * i2;
                int j = f >> 3, kb = f & 7;
                float4 w = *(const float4*)(W_ih0 + (size_t)(j0 + j) * 1024 + k0 + kb * 4);
                Bt[(kb * 4 + 0) * 68 + j] = w.x;
                Bt[(kb * 4 + 1) * 68 + j] = w.y;
                Bt[(kb * 4 + 2) * 68 + j] = w.z;
                Bt[(kb * 4 + 3) * 68 + j] = w.w;
            }
        }
        __syncthreads();
#pragma unroll
        for (int kk = 0; kk < 32; ++kk) {
            float a0 = At[kk * 33 + ty], a1 = At[kk * 33 + ty + 16];
            float4 b4 = *(const float4*)&Bt[kk * 68 + tx * 4];
            acc[0] += a0 * b4.x; acc[1] += a0 * b4.y; acc[2] += a0 * b4.z; acc[3] += a0 * b4.w;
            acc[4] += a1 * b4.x; acc[5] += a1 * b4.y; acc[6] += a1 * b4.z; acc[7] += a1 * b4.w;
        }
    }
    int j = j0 + tx * 4;
    float bi[4] = {b_ih0[j], b_ih0[j + 1], b_ih0[j + 2], b_ih0[j + 3]};
    float bh[4] = {b_hh0[j], b_hh0[j + 1], b_hh0[j + 2], b_hh0[j + 3]};
    float* base = Xpre + (size_t)t * 65536;
#pragma unroll
    for (int c = 0; c < 4; ++c) {
        base[(size_t)(j + c) * 32 + ty]      = acc[c]     + bi[c] + bh[c];
        base[(size_t)(j + c) * 32 + ty + 16] = acc[4 + c] + bi[c] + bh[c];
    }
}

// ---------------- MFMA helper: one MFMA per wave per K-chunk ----------------
// Wave (Mt,kq): handles ktile = ktbase + kq within the loaded chunk of 8 ktiles.
// A operand: lane l holds X[n = Mt*16 + (l&15)][granule = kq*4 + quad] of the chunk.
__device__ __forceinline__ void compute1(f32x4& a0, const us_t* __restrict__ Ab, int ktbase,
                                         int Mt, int kq, int l16, int quad,
                                         const us_t* __restrict__ lw) {
    bf16x8 av = *(const bf16x8*)(Ab + ((size_t)(kq * 4 + quad) * 32 + Mt * 16 + l16) * 8);
    bf16x8 bv = *(const bf16x8*)(lw + (((size_t)(ktbase + kq) * 4 + quad) * 16 + l16) * 8);
    a0 = __builtin_amdgcn_mfma_f32_16x16x32_bf16(av, bv, a0, 0, 0, 0);
}

// ---------------- gate reduction + nonlinearity + publish (8-way K-reduce) ----------------
__device__ __forceinline__ void tail_pub(f32x4 acc, int colbase,
                                         float g0, float g1, float g2, float g3,
                                         float& creg, u32* __restrict__ hOut32,
                                         u32* __restrict__ hT32,
                                         int b, int tid, float* red, float* gv) {
    const int l16 = tid & 15, quad = (tid >> 4) & 3, w = tid >> 6;
    const int Mt = w & 1, kq = w >> 1;
    const int cl = l16 - colbase;
    // red layout: [kq*16 + Mt*8 + cl][20], slot = quad*4 + r  (16B-aligned float4 stores)
    if ((unsigned)cl < 8u) {
        float4 v = {acc[0], acc[1], acc[2], acc[3]};
        *(float4*)&red[((size_t)(kq * 16 + Mt * 8 + cl)) * 20 + quad * 4] = v;
    }
    __syncthreads();
    if (tid < 256) {
        int row = tid >> 4, s = tid & 15;     // row = Mt*8+cl, s = sample-in-group
        float g = 0.0f;
#pragma unroll
        for (int k2 = 0; k2 < 8; ++k2) g += red[((size_t)(k2 * 16 + row)) * 20 + s];
        gv[(row & 7) * 33 + (row >> 3) * 16 + s] = g;
    }
    __syncthreads();
    if (tid < 64) {
        int jl = tid >> 5, n = tid & 31;
        float gi = gv[jl * 33 + n]       + g0;
        float gf = gv[(2 + jl) * 33 + n] + g1;
        float gg = gv[(4 + jl) * 33 + n] + g2;
        float go = gv[(6 + jl) * 33 + n] + g3;
        float cn = sigmf(gf) * creg + sigmf(gi) * tanhf(gg);
        float hn = sigmf(go) * tanhf(cn);
        creg = cn;
        float hO = __shfl_xor(hn, 32);             // partner unit (jl^1), same sample
        if (jl == 0) {
            u32 pk = (u32)f2b(hn) | ((u32)f2b(hO) << 16);
            __hip_atomic_store(hOut32 + (((size_t)(b >> 2) * 32 + n) * 4 + (b & 3)), pk,
                               __ATOMIC_RELAXED, __HIP_MEMORY_SCOPE_AGENT);
            if (hT32)
                __hip_atomic_store(hT32 + (n * 260 + b), pk,
                                   __ATOMIC_RELAXED, __HIP_MEMORY_SCOPE_AGENT);
        }
    }
}

// ---------------- ctx (f32, granule-major) -> bf16 LDS granule; mirror owner granules ----------------
__device__ __forceinline__ void stage_ctx1(us_t* __restrict__ dst, const float* __restrict__ src,
                                           us_t* __restrict__ atbt, int b, int sbase, int tid) {
    int gs = sbase + tid;
    const float* s = src + (size_t)gs * 8;
    float4 a = *(const float4*)s;
    float4 c = *(const float4*)(s + 4);
    u32 w0, w1, w2, w3;
    asm("v_cvt_pk_bf16_f32 %0, %1, %2" : "=v"(w0) : "v"(a.x), "v"(a.y));
    asm("v_cvt_pk_bf16_f32 %0, %1, %2" : "=v"(w1) : "v"(a.z), "v"(a.w));
    asm("v_cvt_pk_bf16_f32 %0, %1, %2" : "=v"(w2) : "v"(c.x), "v"(c.y));
    asm("v_cvt_pk_bf16_f32 %0, %1, %2" : "=v"(w3) : "v"(c.z), "v"(c.w));
    uint4 pk = {w0, w1, w2, w3};
    *(uint4*)(dst + (size_t)tid * 8) = pk;
    if ((gs >> 3) == b) *(uint4*)(atbt + (size_t)gs * 8) = pk;
}

// ---------------- cooperative sequential kernel: 1024 threads, 16 waves, 4/SIMD ----------------
__global__ __launch_bounds__(1024, 1) void k_seq(float* ws,
                                                 const float* __restrict__ enc,
                                                 const float* __restrict__ b_ih1,
                                                 const float* __restrict__ b_hh1) {
    __shared__ __align__(16) us_t lds_w[16384];      // 32 KB: Wq slice [128 r][16 col][8]
    __shared__ __align__(16) us_t lds_e[64 * 552];   // 69 KB enc slice bf16, skewed
    __shared__ __align__(16) us_t Ax[2][8192];       // 2 x 16 KB X granule buffers (K=256 each)
    __shared__ __align__(16) float red_s[8 * 16 * 20]; // 10 KB cross-wave K-reduce
    __shared__ __align__(16) float gv_s[272];

    const int b = blockIdx.x, tid = threadIdx.x;
    const int w = tid >> 6, l16 = tid & 15, quad = (tid >> 4) & 3;
    const int Mt = w & 1, kq = w >> 1;               // kq 0..7
    us_t* Ax0 = Ax[0];
    us_t* Ax1 = Ax[1];

    float* Xpre = ws + OFF_XPRE;
    us_t* h0b = (us_t*)(ws + OFF_H0B);
    us_t* h1b = (us_t*)(ws + OFF_H1B);
    u32*  h1T32 = (u32*)(ws + OFF_H1T);
    us_t* atb = (us_t*)(ws + OFF_ATB);
    float* ctx = ws + OFF_CTX;
    u64*  mz  = (u64*)(ws + OFF_MZ);
    u32* flg = (u32*)(ws + OFF_FLG);

    float c0r = 0.0f, c1r = 0.0f;

    // hoisted P2 bias sums (constant across t)
    float bs0 = 0.f, bs1 = 0.f, bs2 = 0.f, bs3 = 0.f;
    if (tid < 64) {
        int j = b * 2 + (tid >> 5);
        bs0 = b_ih1[j] + b_hh1[j];
        bs1 = b_ih1[512 + j] + b_hh1[512 + j];
        bs2 = b_ih1[1024 + j] + b_hh1[1024 + j];
        bs3 = b_ih1[1536 + j] + b_hh1[1536 + j];
    }

    // ---- one-time LDS residency: weights + enc slice ----
    {
        const uint4* wsrc = (const uint4*)((const us_t*)(ws + OFF_WQ) + (size_t)b * 16384);
        for (int f = tid; f < 2048; f += 1024) ((uint4*)lds_w)[f] = wsrc[f];
        const int n = b >> 3, ts0 = (b & 7) * 64;
        const float4* encn = (const float4*)(enc + ((size_t)n * 512 + ts0) * 512);
#pragma unroll
        for (int j = 0; j < 8; ++j) {
            int f = tid + j * 1024;
            int row = f >> 7, c4 = f & 127;
            float4 v = encn[(size_t)row * 128 + c4];
            ushort4 o;
            o.x = f2b(v.x); o.y = f2b(v.y); o.z = f2b(v.z); o.w = f2b(v.w);
            *(ushort4*)(lds_e + (size_t)row * 552 + (c4 >> 5) * 136 + (c4 & 31) * 4) = o;
        }
    }
    __syncthreads();

    for (int t = 0; t < T_STEPS; ++t) {
        const u32 base = 3u * t;
        // ============ P1: LSTM0, X = [attc(t) k0..511 | h0(t) k512..1023] ============
        float xg0 = 0.f, xg1 = 0.f, xg2 = 0.f, xg3 = 0.f;
        if (tid < 64) {
            const float* xp = Xpre + (size_t)t * 65536;
            int j = b * 2 + (tid >> 5), nn = tid & 31;
            xg0 = xp[(size_t)(0    + j) * 32 + nn];
            xg1 = xp[(size_t)(512  + j) * 32 + nn];
            xg2 = xp[(size_t)(1024 + j) * 32 + nn];
            xg3 = xp[(size_t)(1536 + j) * 32 + nn];
        }
        f32x4 acc;
#pragma unroll
        for (int r = 0; r < 4; ++r) acc[r] = 0.0f;
        {   // h0(t) half first (no barrier dependency): ktiles 16..31
            const us_t* h0s = h0b + (size_t)t * 16384;
            ((uint4*)Ax0)[tid] = ((const uint4*)h0s)[tid];
            __syncthreads();
            uint4 r0 = ((const uint4*)(h0s + 8192))[tid];
            compute1(acc, Ax0, 16, Mt, kq, l16, quad, lds_w);
            ((uint4*)Ax1)[tid] = r0;
            __syncthreads();
            compute1(acc, Ax1, 24, Mt, kq, l16, quad, lds_w);
        }
        wait_all(flg, base, tid);                  // attc(t) (normalized) ready
        {
            const float* cts = ctx + (size_t)t * 16384;
            us_t* atbt = atb + (size_t)t * 16384;
            stage_ctx1(Ax0, cts, atbt, b, 0, tid);
            __syncthreads();
            // prefetch chunk 2 (slots 1024..2047) while computing chunk 1
            float4 pa = *(const float4*)(cts + (size_t)(1024 + tid) * 8);
            float4 pc = *(const float4*)(cts + (size_t)(1024 + tid) * 8 + 4);
            compute1(acc, Ax0, 0, Mt, kq, l16, quad, lds_w);
            {
                u32 w0, w1, w2, w3;
                asm("v_cvt_pk_bf16_f32 %0, %1, %2" : "=v"(w0) : "v"(pa.x), "v"(pa.y));
                asm("v_cvt_pk_bf16_f32 %0, %1, %2" : "=v"(w1) : "v"(pa.z), "v"(pa.w));
                asm("v_cvt_pk_bf16_f32 %0, %1, %2" : "=v"(w2) : "v"(pc.x), "v"(pc.y));
                asm("v_cvt_pk_bf16_f32 %0, %1, %2" : "=v"(w3) : "v"(pc.z), "v"(pc.w));
                uint4 pk = {w0, w1, w2, w3};
                *(uint4*)(Ax1 + (size_t)tid * 8) = pk;
                int gs = 1024 + tid;
                if ((gs >> 3) == b) *(uint4*)(atbt + (size_t)gs * 8) = pk;
            }
            __syncthreads();
            compute1(acc, Ax1, 8, Mt, kq, l16, quad, lds_w);
        }
        tail_pub(acc, 0, xg0, xg1, xg2, xg3, c0r,
                 (u32*)(h0b + (size_t)(t + 1) * 16384), nullptr, b, tid, red_s, gv_s);
        arrive(flg, b, tid, base + 1);
        // ============ P2: LSTM1, X = [h0(t+1) k0..511 | h1(t) k512..1023] ============
#pragma unroll
        for (int r = 0; r < 4; ++r) acc[r] = 0.0f;
        {   // h1(t) half first: ktiles 16..31
            const us_t* h1s = h1b + (size_t)t * 16384;
            ((uint4*)Ax0)[tid] = ((const uint4*)h1s)[tid];
            __syncthreads();
            uint4 r0 = ((const uint4*)(h1s + 8192))[tid];
            compute1(acc, Ax0, 16, Mt, kq, l16, quad, lds_w);
            ((uint4*)Ax1)[tid] = r0;
            __syncthreads();
            compute1(acc, Ax1, 24, Mt, kq, l16, quad, lds_w);
        }
        wait_all(flg, base + 1, tid);
        {
            const us_t* h0n = h0b + (size_t)(t + 1) * 16384;
            ((uint4*)Ax0)[tid] = ((const uint4*)h0n)[tid];
            __syncthreads();
            uint4 r0 = ((const uint4*)(h0n + 8192))[tid];
            compute1(acc, Ax0, 0, Mt, kq, l16, quad, lds_w);
            ((uint4*)Ax1)[tid] = r0;
            __syncthreads();
            compute1(acc, Ax1, 8, Mt, kq, l16, quad, lds_w);
        }
        tail_pub(acc, 8, bs0, bs1, bs2, bs3, c1r,
                 (u32*)(h1b + (size_t)(t + 1) * 16384),
                 h1T32 + (size_t)(t + 1) * 8320, b, tid, red_s, gv_s);
        arrive(flg, b, tid, base + 2);
        // ============ ATTN: single-pass, 8 blocks/sample, mini-sync + normalized atomic ctx ============
        wait_all(flg, base + 2, tid);
        {
            const int n = b >> 3, c = b & 7;
            float* h_l = (float*)Ax0;      // 512 f
            float* scp = h_l + 512;        // [16][66] = 1056 f
            float* p_l = h_l + 1568;       // 64 f
            float* aux = h_l + 1632;       // 2 f
            if (tid < 256) {
                u32 hv = h1T32[(size_t)(t + 1) * 8320 + n * 260 + tid];
                float2 h2 = {bfl(hv), bfh(hv)};
                *(float2*)(h_l + tid * 2) = h2;
            }
            __syncthreads();
            {
                int ti = tid >> 4, kp = tid & 15;
                const us_t* er = lds_e + (size_t)ti * 552 + (kp >> 2) * 136 + (kp & 3) * 32;
                const float* hr = h_l + (kp >> 2) * 128 + (kp & 3) * 32;
                float s = 0.0f;
#pragma unroll
                for (int k8 = 0; k8 < 4; ++k8) {
                    uint4 u = *(const uint4*)(er + k8 * 8);
                    const float* h8 = hr + k8 * 8;
                    s += bfl(u.x) * h8[0] + bfh(u.x) * h8[1]
                       + bfl(u.y) * h8[2] + bfh(u.y) * h8[3]
                       + bfl(u.z) * h8[4] + bfh(u.z) * h8[5]
                       + bfl(u.w) * h8[6] + bfh(u.w) * h8[7];
                }
                scp[kp * 66 + ti] = s;
            }
            __syncthreads();
            if (tid < 64) {
                float sc = 0.0f;
#pragma unroll
                for (int kp = 0; kp < 16; ++kp) sc += scp[kp * 66 + tid];
                float m = sc;
                for (int o = 32; o; o >>= 1) m = fmaxf(m, __shfl_xor(m, o));
                float e = __expf(sc - m);
                float z = e;
                for (int o = 32; o; o >>= 1) z += __shfl_xor(z, o);
                p_l[tid] = e;
                if (tid == 0) {
                    aux[0] = m;      // own chunk max
                    u64 pk = ((u64)__float_as_uint(m) << 32) | (u64)__float_as_uint(z);
                    __hip_atomic_store(mz + ((size_t)(t + 1) * 256 + n * 8 + c), pk,
                                       __ATOMIC_RELAXED, __HIP_MEMORY_SCOPE_AGENT);
                }
            }
            // mini-sync among the 8 chunk blocks of this sample -> global (M, Z)
            if (tid < 8) {
                u64 v;
                for (;;) {
                    v = __hip_atomic_load(mz + ((size_t)(t + 1) * 256 + n * 8 + tid),
                                          __ATOMIC_RELAXED, __HIP_MEMORY_SCOPE_AGENT);
                    if ((u32)v != 0u) break;
                    __builtin_amdgcn_s_sleep(1);
                }
                float mi = __uint_as_float((u32)(v >> 32));
                float zi = __uint_as_float((u32)v);
#pragma unroll
                for (int o = 1; o < 8; o <<= 1) {
                    float mo = __shfl_xor(mi, o);
                    float zo = __shfl_xor(zi, o);
                    float Mn = fmaxf(mi, mo);
                    zi = zi * __expf(mi - Mn) + zo * __expf(mo - Mn);
                    mi = Mn;
                }
                if (tid == 0)
                    aux[1] = __expf(aux[0] - mi) / zi;   // normalized scale for this chunk
            }
            __syncthreads();
            float scl = aux[1];
            if (tid < 512) {
                int d = tid;
                const us_t* eb = lds_e + (d >> 7) * 136 + (d & 127);
                float cv = 0.0f;
#pragma unroll 8
                for (int ti2 = 0; ti2 < 64; ++ti2)
                    cv += p_l[ti2] * bfl((u32)eb[(size_t)ti2 * 552]);
                int gs = (d >> 3) * 32 + n;
                float* dst = ctx + (size_t)(t + 1) * 16384 + (size_t)gs * 8 + (d & 7);
                __hip_atomic_fetch_add(dst, cv * scl, __ATOMIC_RELAXED, __HIP_MEMORY_SCOPE_AGENT);
            }
        }
        arrive(flg, b, tid, base + 3);
    }
    // tail: materialize bf16 attc(129) for k_mlp (ctx already normalized)
    wait_all(flg, 3u * T_STEPS, tid);
    if (tid < 8) {
        int gs = b * 8 + tid;
        const float* s = ctx + (size_t)129 * 16384 + (size_t)gs * 8;
        float4 a = *(const float4*)s;
        float4 c = *(const float4*)(s + 4);
        u32 w0, w1, w2, w3;
        asm("v_cvt_pk_bf16_f32 %0, %1, %2" : "=v"(w0) : "v"(a.x), "v"(a.y));
        asm("v_cvt_pk_bf16_f32 %0, %1, %2" : "=v"(w1) : "v"(a.z), "v"(a.w));
        asm("v_cvt_pk_bf16_f32 %0, %1, %2" : "=v"(w2) : "v"(c.x), "v"(c.y));
        asm("v_cvt_pk_bf16_f32 %0, %1, %2" : "=v"(w3) : "v"(c.z), "v"(c.w));
        uint4 pk = {w0, w1, w2, w3};
        *(uint4*)(atb + (size_t)129 * 16384 + (size_t)gs * 8) = pk;
    }
}

// ---------------- MLP hidden GEMM (granule-major bf16 in, bf16 out) ----------------
__global__ __launch_bounds__(256) void k_mlp(const us_t* __restrict__ h1b,
                                             const us_t* __restrict__ atb,
                                             const float* __restrict__ W1,
                                             const float* __restrict__ b1,
                                             us_t* __restrict__ hidb) {
    __shared__ __align__(16) float At[32 * 33];
    __shared__ __align__(16) float Bt[32 * 68];
    const int t = blockIdx.x, j0 = blockIdx.y * 64, tid = threadIdx.x;
    const int ty = tid >> 4, tx = tid & 15;
    float acc[8];
#pragma unroll
    for (int i = 0; i < 8; ++i) acc[i] = 0.0f;
    for (int k0 = 0; k0 < 1024; k0 += 32) {
        const us_t* src = (k0 < 512) ? (h1b + (size_t)(t + 1) * 16384 + (size_t)k0 * 32)
                                     : (atb + (size_t)t * 16384 + (size_t)(k0 - 512) * 32);
        __syncthreads();
        if (tid < 128) {   // 32k x 32n tile = 4 granule-rows
            int g8l = tid >> 5, n = tid & 31;
            uint4 v = *(const uint4*)(src + ((size_t)g8l * 32 + n) * 8);
            float* a = At + (size_t)(g8l * 8) * 33 + n;
            a[0]   = bfl(v.x); a[33]  = bfh(v.x);
            a[66]  = bfl(v.y); a[99]  = bfh(v.y);
            a[132] = bfl(v.z); a[165] = bfh(v.z);
            a[198] = bfl(v.w); a[231] = bfh(v.w);
        }
        {
#pragma unroll
            for (int i2 = 0; i2 < 2; ++i2) {
                int f = tid + 256 * i2;
                int j = f >> 3, kb = f & 7;
                float4 wv = *(const float4*)(W1 + (size_t)(j0 + j) * 1024 + k0 + kb * 4);
                Bt[(kb * 4 + 0) * 68 + j] = wv.x;
                Bt[(kb * 4 + 1) * 68 + j] = wv.y;
                Bt[(kb * 4 + 2) * 68 + j] = wv.z;
                Bt[(kb * 4 + 3) * 68 + j] = wv.w;
            }
        }
        __syncthreads();
#pragma unroll
        for (int kk = 0; kk < 32; ++kk) {
            float a0 = At[kk * 33 + ty], a1 = At[kk * 33 + ty + 16];
            float4 b4 = *(const float4*)&Bt[kk * 68 + tx * 4];
            acc[0] += a0 * b4.x; acc[1] += a0 * b4.y; acc[2] += a0 * b4.z; acc[3] += a0 * b4.w;
            acc[4] += a1 * b4.x; acc[5] += a1 * b4.y; acc[6] += a1 * b4.z; acc[7] += a1 * b4.w;
        }
    }
    int j = j0 + tx * 4;
    float4 bv = *(const float4*)(b1 + j);
    int r0 = t * 32;
    ushort4 p0 = {f2b(tanhf(acc[0] + bv.x)), f2b(tanhf(acc[1] + bv.y)),
                  f2b(tanhf(acc[2] + bv.z)), f2b(tanhf(acc[3] + bv.w))};
    ushort4 p1 = {f2b(tanhf(acc[4] + bv.x)), f2b(tanhf(acc[5] + bv.y)),
                  f2b(tanhf(acc[6] + bv.z)), f2b(tanhf(acc[7] + bv.w))};
    *(ushort4*)(hidb + (size_t)(r0 + ty) * 512 + j) = p0;
    *(ushort4*)(hidb + (size_t)(r0 + ty + 16) * 512 + j) = p1;
}

// ---------------- MFMA logits + chunk logsumexp (unchanged) ----------------
__global__ __launch_bounds__(256) void k_ce(const us_t* __restrict__ hidb,
                                            const us_t* __restrict__ W2p,
                                            const float* __restrict__ b2,
                                            const int* __restrict__ padded,
                                            float* __restrict__ cpm, float* __restrict__ cps,
                                            float* __restrict__ tgt) {
    __shared__ __align__(16) us_t Ash[32 * 520];
    __shared__ __align__(16) float lg[256 * 33];
    __shared__ float mred[8 * 32];
    __shared__ float Mf[32];
    __shared__ float sred[8 * 32];
    const int t = blockIdx.x, vc = blockIdx.y, tid = threadIdx.x;
    {
        const uint4* src = (const uint4*)(hidb + (size_t)t * 32 * 512);
#pragma unroll
        for (int i = 0; i < 8; ++i) {
            int f = tid + i * 256;
            uint4 v = src[f];
            *(uint4*)(Ash + (size_t)(f >> 6) * 520 + (f & 63) * 8) = v;
        }
    }
    __syncthreads();
    const int w = tid >> 6, lane = tid & 63;
    const int quad = lane >> 4, l16 = lane & 15;
    f32x4 acc[2][4];
#pragma unroll
    for (int mt = 0; mt < 2; ++mt)
#pragma unroll
        for (int nt = 0; nt < 4; ++nt)
#pragma unroll
            for (int r = 0; r < 4; ++r) acc[mt][nt][r] = 0.0f;
    const int vbase = vc * 256 + w * 64;
    for (int ks = 0; ks < 16; ++ks) {
        bf16x8 a0 = *(const bf16x8*)(Ash + (size_t)(l16)      * 520 + ks * 32 + quad * 8);
        bf16x8 a1 = *(const bf16x8*)(Ash + (size_t)(16 + l16) * 520 + ks * 32 + quad * 8);
        const us_t* bp = W2p + ((size_t)(ks * 4 + quad) * 4096 + vbase + l16) * 8;
#pragma unroll
        for (int nt = 0; nt < 4; ++nt) {
            bf16x8 bb = *(const bf16x8*)(bp + nt * 128);
            acc[0][nt] = __builtin_amdgcn_mfma_f32_16x16x32_bf16(a0, bb, acc[0][nt], 0, 0, 0);
            acc[1][nt] = __builtin_amdgcn_mfma_f32_16x16x32_bf16(a1, bb, acc[1][nt], 0, 0, 0);
        }
    }
#pragma unroll
    for (int nt = 0; nt < 4; ++nt) {
        int vloc = w * 64 + nt * 16 + l16;
        int vglob = vc * 256 + vloc;
        float bias = (vglob < V) ? b2[vglob] : -1e30f;
#pragma unroll
        for (int mt = 0; mt < 2; ++mt)
#pragma unroll
            for (int r = 0; r < 4; ++r)
                lg[vloc * 33 + mt * 16 + quad * 4 + r] = acc[mt][nt][r] + bias;
    }
    __syncthreads();
    {
        int n = tid & 31, c = tid >> 5;
        float m = -1e30f;
        for (int i = 0; i < 32; ++i) m = fmaxf(m, lg[(c * 32 + i) * 33 + n]);
        mred[c * 32 + n] = m;
    }
    __syncthreads();
    if (tid < 32) {
        float M = mred[tid];
#pragma unroll
        for (int c = 1; c < 8; ++c) M = fmaxf(M, mred[c * 32 + tid]);
        Mf[tid] = M;
    }
    __syncthreads();
    {
        int n = tid & 31, c = tid >> 5;
        float M = Mf[n], s = 0.0f;
        for (int i = 0; i < 32; ++i) s += __expf(lg[(c * 32 + i) * 33 + n] - M);
        sred[c * 32 + n] = s;
    }
    __syncthreads();
    if (tid < 32) {
        int n = tid;
        float S = 0.0f;
#pragma unroll
        for (int c = 0; c < 8; ++c) S += sred[c * 32 + n];
        int r = t * 32 + n;
        cpm[(size_t)r * 16 + vc] = Mf[n];
        cps[(size_t)r * 16 + vc] = S;
        int vstar = (t < 128) ? padded[n * 128 + t] : 2;
        int vl = vstar - vc * 256;
        if (vl >= 0 && vl < 256) tgt[r] = lg[vl * 33 + n];
    }
}

// ---------------- final combine + CE reduction (unchanged) ----------------
__global__ __launch_bounds__(256) void k_final(const float* __restrict__ cpm,
                                               const float* __restrict__ cps,
                                               const float* __restrict__ tgt,
                                               float* __restrict__ out) {
    __shared__ float red[256];
    float local = 0.0f;
    for (int r = threadIdx.x; r < 4128; r += 256) {
        float M = -1e30f;
#pragma unroll
        for (int c = 0; c < 16; ++c) M = fmaxf(M, cpm[(size_t)r * 16 + c]);
        float S = 0.0f;
#pragma unroll
        for (int c = 0; c < 16; ++c) S += cps[(size_t)r * 16 + c] * __expf(cpm[(size_t)r * 16 + c] - M);
        local += (M + logf(S)) - tgt[r];
    }
    red[threadIdx.x] = local;
    __syncthreads();
    for (int o = 128; o; o >>= 1) {
        if (threadIdx.x < o) red[threadIdx.x] += red[threadIdx.x + o];
        __syncthreads();
    }
    if (threadIdx.x == 0) out[0] = red[0] * (128.0f / 4128.0f);
}

extern "C" void kernel_launch(void* const* d_in, const int* in_sizes, int n_in,
                              void* d_out, int out_size, void* d_ws, size_t ws_size,
                              hipStream_t stream) {
    const int*   padded = (const int*)d_in[0];
    const float* enc    = (const float*)d_in[1];
    const float* emb    = (const float*)d_in[2];
    const float* W_ih0  = (const float*)d_in[3];
    const float* b_ih0  = (const float*)d_in[4];
    const float* W_hh0  = (const float*)d_in[5];
    const float* b_hh0  = (const float*)d_in[6];
    const float* W_ih1  = (const float*)d_in[7];
    const float* b_ih1  = (const float*)d_in[8];
    const float* W_hh1  = (const float*)d_in[9];
    const float* b_hh1  = (const float*)d_in[10];
    const float* W1     = (const float*)d_in[11];
    const float* b1     = (const float*)d_in[12];
    const float* W2     = (const float*)d_in[13];
    const float* b2     = (const float*)d_in[14];
    float* ws  = (float*)d_ws;
    float* out = (float*)d_out;

    hipLaunchKernelGGL(k_init, dim3(640), dim3(256), 0, stream, ws);
    hipLaunchKernelGGL(k_packWq, dim3(16384), dim3(256), 0, stream,
                       W_ih0, W_hh0, W_ih1, W_hh1, (us_t*)(ws + OFF_WQ));
    hipLaunchKernelGGL(k_packW2, dim3(8192), dim3(256), 0, stream,
                       W2, (us_t*)(ws + OFF_W2P));
    hipLaunchKernelGGL(k_xpre, dim3(129, 32), dim3(256), 0, stream,
                       padded, emb, W_ih0, b_ih0, b_hh0, ws + OFF_XPRE);
    {
        float* ws_a = ws;
        const float* enc_a = enc;
        const float* bia = b_ih1;
        const float* bib = b_hh1;
        void* args[] = {(void*)&ws_a, (void*)&enc_a, (void*)&bia, (void*)&bib};
        hipLaunchCooperativeKernel((void*)k_seq, dim3(256), dim3(1024), args, 0, stream);
    }
    hipLaunchKernelGGL(k_mlp, dim3(129, 8), dim3(256), 0, stream,
                       (const us_t*)(ws + OFF_H1B), (const us_t*)(ws + OFF_ATB), W1, b1,
                       (us_t*)(ws + OFF_HID));
    hipLaunchKernelGGL(k_ce, dim3(129, 16), dim3(256), 0, stream,
                       (const us_t*)(ws + OFF_HID), (const us_t*)(ws + OFF_W2P), b2, padded,
                       ws + OFF_CPM, ws + OFF_CPS, ws + OFF_TGT);
    hipLaunchKernelGGL(k_final, dim3(1), dim3(256), 0, stream,
                       ws + OFF_CPM, ws + OFF_CPS, ws + OFF_TGT, out);
}

// Round 3
// 2131.760 us; speedup vs baseline: 1.7231x; 1.0904x over previous
//
#include <hip/hip_runtime.h>

typedef unsigned short us_t;
typedef unsigned int u32;
typedef unsigned long long u64;
typedef __attribute__((ext_vector_type(8))) short bf16x8;
typedef __attribute__((ext_vector_type(4))) float f32x4;

// Problem constants
constexpr int V = 4000, E = 512, H = 512, NB = 32, To = 128, Ti = 512;
constexpr int T_STEPS = 129;          // To + 1

// ws layout (float offsets)
constexpr size_t OFF_XPRE = 0;                                   // f [129][2048][32] (transposed)
constexpr size_t OFF_WQ   = OFF_XPRE + (size_t)129*32*2048;      // us [256 b][128 r][16 col][8] packed B tiles
constexpr size_t OFF_H0B  = OFF_WQ + (size_t)256*128*16*8/2;     // us [130][64 g8][32 n][8] granule-major
constexpr size_t OFF_H1B  = OFF_H0B + (size_t)130*16384/2;       // us [130][64][32][8]
constexpr size_t OFF_H1T  = OFF_H1B + (size_t)130*16384/2;       // us [130][32][520] transposed h1 for attn
constexpr size_t OFF_ATB  = OFF_H1T + (size_t)130*16640/2;       // us [130][64][32][8] bf16 attc (granule-major)
constexpr size_t OFF_CTX  = OFF_ATB + (size_t)130*16384/2;       // f [130][64][32][8] atomic acc (normalized)
constexpr size_t OFF_MZ   = OFF_CTX + (size_t)130*16384;         // u64 [130][256]
constexpr size_t OFF_HID  = OFF_MZ + (size_t)130*256*2;          // us [4128][512] bf16 hidden
constexpr size_t OFF_W2P  = OFF_HID + (size_t)4128*512;          // us [64][4096][8] packed W2
constexpr size_t OFF_CPM  = OFF_W2P + (size_t)64*4096*8/2;       // f [4128][16]
constexpr size_t OFF_CPS  = OFF_CPM + (size_t)4128*16;
constexpr size_t OFF_TGT  = OFF_CPS + (size_t)4128*16;           // f [4128]
constexpr size_t OFF_FLG  = OFF_TGT + 4128;                      // u32 [256] dense flags

__device__ __forceinline__ float sigmf(float x) { return 1.0f / (1.0f + __expf(-x)); }
__device__ __forceinline__ float tanh_fast(float x) {
    float e = __expf(-2.0f * fabsf(x));
    float t = (1.0f - e) / (1.0f + e);
    return copysignf(t, x);
}
__device__ __forceinline__ float bfl(u32 u) { return __uint_as_float(u << 16); }
__device__ __forceinline__ float bfh(u32 u) { return __uint_as_float(u & 0xffff0000u); }
__device__ __forceinline__ us_t f2b(float x) {
    u32 u = __float_as_uint(x);
    return (us_t)((u + 0x7fffu + ((u >> 16) & 1u)) >> 16);
}
__device__ __forceinline__ uint4 cvt_pk8(float4 a, float4 c) {
    u32 w0, w1, w2, w3;
    asm("v_cvt_pk_bf16_f32 %0, %1, %2" : "=v"(w0) : "v"(a.x), "v"(a.y));
    asm("v_cvt_pk_bf16_f32 %0, %1, %2" : "=v"(w1) : "v"(a.z), "v"(a.w));
    asm("v_cvt_pk_bf16_f32 %0, %1, %2" : "=v"(w2) : "v"(c.x), "v"(c.y));
    asm("v_cvt_pk_bf16_f32 %0, %1, %2" : "=v"(w3) : "v"(c.z), "v"(c.w));
    uint4 pk = {w0, w1, w2, w3};
    return pk;
}

// ---- grid sync: dense per-block epoch flags (unchanged protocol) ----
__device__ __forceinline__ void arrive(u32* flg, int b, int tid, u32 val) {
    __syncthreads();
    if (tid == 0)
        __hip_atomic_store(flg + b, val, __ATOMIC_RELAXED, __HIP_MEMORY_SCOPE_AGENT);
}
__device__ __forceinline__ void wait_all(u32* flg, u32 target, int tid) {
    if (tid < 128) {
        const u64* f8 = (const u64*)flg;
        bool done = false;
        for (;;) {
            if (!done) {
                u64 v = __hip_atomic_load(f8 + tid, __ATOMIC_RELAXED, __HIP_MEMORY_SCOPE_AGENT);
                done = ((u32)v >= target) && ((u32)(v >> 32) >= target);
            }
            if (__all((int)done)) break;
            __builtin_amdgcn_s_sleep(2);
        }
    }
    __syncthreads();
}

// ---------------- init ----------------
__global__ __launch_bounds__(256) void k_init(float* ws) {
    int t0 = blockIdx.x * 256 + threadIdx.x;
    int nth = gridDim.x * 256;
    float4 z4 = {0.f, 0.f, 0.f, 0.f};
    float4* c4 = (float4*)(ws + OFF_CTX);
    for (int i = t0; i < 130 * 32 * 128; i += nth) c4[i] = z4;
    float4* m4 = (float4*)(ws + OFF_MZ);
    for (int i = t0; i < 130 * 128; i += nth) m4[i] = z4;
    float4* h04 = (float4*)(ws + OFF_H0B);
    float4* h14 = (float4*)(ws + OFF_H1B);
    for (int i = t0; i < 2048; i += nth) { h04[i] = z4; h14[i] = z4; }
    u32* fl = (u32*)(ws + OFF_FLG);
    if (t0 < 256) fl[t0] = 0u;
}

// ---------------- weight pre-pack for MFMA B operand (unchanged) ----------------
__global__ __launch_bounds__(256) void k_packWq(const float* __restrict__ W_ih0,
                                                const float* __restrict__ W_hh0,
                                                const float* __restrict__ W_ih1,
                                                const float* __restrict__ W_hh1,
                                                us_t* __restrict__ Wq) {
    int p = blockIdx.x * 256 + threadIdx.x;        // 0..4194303
    int j = p & 7, col = (p >> 3) & 15, r = (p >> 7) & 127, b = p >> 14;
    int k = r * 8 + j;
    int cl = col & 7;
    int gRow = (cl >> 1) * 512 + b * 2 + (cl & 1);
    float v;
    if (col < 8)
        v = (k < 512) ? W_ih0[(size_t)gRow * 1024 + 512 + k]
                      : W_hh0[(size_t)gRow * 512 + (k - 512)];
    else
        v = (k < 512) ? W_ih1[(size_t)gRow * 512 + k]
                      : W_hh1[(size_t)gRow * 512 + (k - 512)];
    Wq[p] = f2b(v);
}

// ---------------- W2 pre-pack (unchanged) ----------------
__global__ __launch_bounds__(256) void k_packW2(const float* __restrict__ W2,
                                                us_t* __restrict__ W2p) {
    int p = blockIdx.x * 256 + threadIdx.x;
    int j = p & 7, v = (p >> 3) & 4095, kb = p >> 15;
    float x = (v < V) ? W2[(size_t)v * 512 + kb * 8 + j] : 0.0f;
    W2p[p] = f2b(x);
}

// ---------------- X_pre GEMM (unchanged, f32) ----------------
__global__ __launch_bounds__(256) void k_xpre(const int* __restrict__ padded,
                                              const float* __restrict__ embedding,
                                              const float* __restrict__ W_ih0,
                                              const float* __restrict__ b_ih0,
                                              const float* __restrict__ b_hh0,
                                              float* __restrict__ Xpre) {
    __shared__ __align__(16) float At[32 * 33];
    __shared__ __align__(16) float Bt[32 * 68];
    __shared__ int toks[32];
    const int t = blockIdx.x, j0 = blockIdx.y * 64, tid = threadIdx.x;
    if (tid < 32) toks[tid] = (t == 0) ? 1 : padded[tid * 128 + (t - 1)];
    __syncthreads();
    const int ty = tid >> 4, tx = tid & 15;
    float acc[8];
#pragma unroll
    for (int i = 0; i < 8; ++i) acc[i] = 0.0f;
    for (int k0 = 0; k0 < 512; k0 += 32) {
        __syncthreads();
        {
            int r = tid >> 3, kk4 = tid & 7;
            float4 v = *(const float4*)(embedding + (size_t)toks[r] * 512 + k0 + kk4 * 4);
            At[(kk4 * 4 + 0) * 33 + r] = v.x;
            At[(kk4 * 4 + 1) * 33 + r] = v.y;
            At[(kk4 * 4 + 2) * 33 + r] = v.z;
            At[(kk4 * 4 + 3) * 33 + r] = v.w;
#pragma unroll
            for (int i2 = 0; i2 < 2; ++i2) {
                int f = tid + 256 * i2;
                int j = f >> 3, kb = f & 7;
                float4 w = *(const float4*)(W_ih0 + (size_t)(j0 + j) * 1024 + k0 + kb * 4);
                Bt[(kb * 4 + 0) * 68 + j] = w.x;
                Bt[(kb * 4 + 1) * 68 + j] = w.y;
                Bt[(kb * 4 + 2) * 68 + j] = w.z;
                Bt[(kb * 4 + 3) * 68 + j] = w.w;
            }
        }
        __syncthreads();
#pragma unroll
        for (int kk = 0; kk < 32; ++kk) {
            float a0 = At[kk * 33 + ty], a1 = At[kk * 33 + ty + 16];
            float4 b4 = *(const float4*)&Bt[kk * 68 + tx * 4];
            acc[0] += a0 * b4.x; acc[1] += a0 * b4.y; acc[2] += a0 * b4.z; acc[3] += a0 * b4.w;
            acc[4] += a1 * b4.x; acc[5] += a1 * b4.y; acc[6] += a1 * b4.z; acc[7] += a1 * b4.w;
        }
    }
    int j = j0 + tx * 4;
    float bi[4] = {b_ih0[j], b_ih0[j + 1], b_ih0[j + 2], b_ih0[j + 3]};
    float bh[4] = {b_hh0[j], b_hh0[j + 1], b_hh0[j + 2], b_hh0[j + 3]};
    float* base = Xpre + (size_t)t * 65536;
#pragma unroll
    for (int c = 0; c < 4; ++c) {
        base[(size_t)(j + c) * 32 + ty]      = acc[c]     + bi[c] + bh[c];
        base[(size_t)(j + c) * 32 + ty + 16] = acc[4 + c] + bi[c] + bh[c];
    }
}

// ---------------- MFMA helper: one MFMA per wave per K-chunk ----------------
__device__ __forceinline__ void compute1(f32x4& a0, const us_t* __restrict__ Ab, int ktbase,
                                         int Mt, int kq, int l16, int quad,
                                         const us_t* __restrict__ lw) {
    bf16x8 av = *(const bf16x8*)(Ab + ((size_t)(kq * 4 + quad) * 32 + Mt * 16 + l16) * 8);
    bf16x8 bv = *(const bf16x8*)(lw + (((size_t)(ktbase + kq) * 4 + quad) * 16 + l16) * 8);
    a0 = __builtin_amdgcn_mfma_f32_16x16x32_bf16(av, bv, a0, 0, 0, 0);
}

// ---------------- gate reduction + nonlinearity + publish (8-way K-reduce) ----------------
__device__ __forceinline__ void tail_pub(f32x4 acc, int colbase,
                                         float g0, float g1, float g2, float g3,
                                         float& creg, u32* __restrict__ hOut32,
                                         u32* __restrict__ hT32,
                                         int b, int tid, float* red, float* gv) {
    const int l16 = tid & 15, quad = (tid >> 4) & 3, w = tid >> 6;
    const int Mt = w & 1, kq = w >> 1;
    const int cl = l16 - colbase;
    // red layout: [kq*16 + Mt*8 + cl][20], slot = quad*4 + r  (16B-aligned float4 stores)
    if ((unsigned)cl < 8u) {
        float4 v = {acc[0], acc[1], acc[2], acc[3]};
        *(float4*)&red[((size_t)(kq * 16 + Mt * 8 + cl)) * 20 + quad * 4] = v;
    }
    __syncthreads();
    if (tid < 256) {
        int row = tid >> 4, s = tid & 15;     // row = Mt*8+cl, s = sample-in-group
        float g = 0.0f;
#pragma unroll
        for (int k2 = 0; k2 < 8; ++k2) g += red[((size_t)(k2 * 16 + row)) * 20 + s];
        gv[(row & 7) * 33 + (row >> 3) * 16 + s] = g;
    }
    __syncthreads();
    if (tid < 64) {
        int jl = tid >> 5, n = tid & 31;
        float gi = gv[jl * 33 + n]       + g0;
        float gf = gv[(2 + jl) * 33 + n] + g1;
        float gg = gv[(4 + jl) * 33 + n] + g2;
        float go = gv[(6 + jl) * 33 + n] + g3;
        float cn = sigmf(gf) * creg + sigmf(gi) * tanh_fast(gg);
        float hn = sigmf(go) * tanh_fast(cn);
        creg = cn;
        float hO = __shfl_xor(hn, 32);             // partner unit (jl^1), same sample
        if (jl == 0) {
            u32 pk = (u32)f2b(hn) | ((u32)f2b(hO) << 16);
            __hip_atomic_store(hOut32 + (((size_t)(b >> 2) * 32 + n) * 4 + (b & 3)), pk,
                               __ATOMIC_RELAXED, __HIP_MEMORY_SCOPE_AGENT);
            if (hT32)
                __hip_atomic_store(hT32 + (n * 260 + b), pk,
                                   __ATOMIC_RELAXED, __HIP_MEMORY_SCOPE_AGENT);
        }
    }
}

// ---------------- cooperative sequential kernel: 1024 threads, 16 waves, 4/SIMD ----------------
__global__ __launch_bounds__(1024, 1) void k_seq(float* ws,
                                                 const float* __restrict__ enc,
                                                 const float* __restrict__ b_ih1,
                                                 const float* __restrict__ b_hh1) {
    __shared__ __align__(16) us_t lds_w[16384];      // 32 KB: Wq slice [128 r][16 col][8]
    __shared__ __align__(16) us_t lds_e[64 * 552];   // 69 KB enc slice bf16, skewed
    __shared__ __align__(16) us_t Ax[2][8192];       // 2 x 16 KB X granule buffers (K=256 each)
    __shared__ __align__(16) float red_s[8 * 16 * 20]; // 10 KB cross-wave K-reduce
    __shared__ __align__(16) float gv_s[272];

    const int b = blockIdx.x, tid = threadIdx.x;
    const int w = tid >> 6, l16 = tid & 15, quad = (tid >> 4) & 3;
    const int Mt = w & 1, kq = w >> 1;               // kq 0..7
    us_t* Ax0 = Ax[0];
    us_t* Ax1 = Ax[1];

    float* Xpre = ws + OFF_XPRE;
    us_t* h0b = (us_t*)(ws + OFF_H0B);
    us_t* h1b = (us_t*)(ws + OFF_H1B);
    u32*  h1T32 = (u32*)(ws + OFF_H1T);
    us_t* atb = (us_t*)(ws + OFF_ATB);
    float* ctx = ws + OFF_CTX;
    u64*  mz  = (u64*)(ws + OFF_MZ);
    u32* flg = (u32*)(ws + OFF_FLG);

    // XCD-affinity attention mapping: sample n = b&31, chunk c = b>>5.
    // The 8 chunk blocks of a sample are congruent mod 32 (hence mod 8) ->
    // same XCD under round-robin dispatch -> mz/ctx exchange stays L2-local.
    const int an = b & 31, ac = b >> 5;

    float c0r = 0.0f, c1r = 0.0f;

    // hoisted P2 bias sums (constant across t)
    float bs0 = 0.f, bs1 = 0.f, bs2 = 0.f, bs3 = 0.f;
    if (tid < 64) {
        int j = b * 2 + (tid >> 5);
        bs0 = b_ih1[j] + b_hh1[j];
        bs1 = b_ih1[512 + j] + b_hh1[512 + j];
        bs2 = b_ih1[1024 + j] + b_hh1[1024 + j];
        bs3 = b_ih1[1536 + j] + b_hh1[1536 + j];
    }

    // ---- one-time LDS residency: weights + enc slice ----
    {
        const uint4* wsrc = (const uint4*)((const us_t*)(ws + OFF_WQ) + (size_t)b * 16384);
        for (int f = tid; f < 2048; f += 1024) ((uint4*)lds_w)[f] = wsrc[f];
        const int ts0 = ac * 64;
        const float4* encn = (const float4*)(enc + ((size_t)an * 512 + ts0) * 512);
#pragma unroll
        for (int j = 0; j < 8; ++j) {
            int f = tid + j * 1024;
            int row = f >> 7, c4 = f & 127;
            float4 v = encn[(size_t)row * 128 + c4];
            ushort4 o;
            o.x = f2b(v.x); o.y = f2b(v.y); o.z = f2b(v.z); o.w = f2b(v.w);
            *(ushort4*)(lds_e + (size_t)row * 552 + (c4 >> 5) * 136 + (c4 & 31) * 4) = o;
        }
    }
    __syncthreads();

    for (int t = 0; t < T_STEPS; ++t) {
        const u32 base = 3u * t;
        // ============ P1: LSTM0, X = [attc(t) k0..511 | h0(t) k512..1023] ============
        float xg0 = 0.f, xg1 = 0.f, xg2 = 0.f, xg3 = 0.f;
        if (tid < 64) {
            const float* xp = Xpre + (size_t)t * 65536;
            int j = b * 2 + (tid >> 5), nn = tid & 31;
            xg0 = xp[(size_t)(0    + j) * 32 + nn];
            xg1 = xp[(size_t)(512  + j) * 32 + nn];
            xg2 = xp[(size_t)(1024 + j) * 32 + nn];
            xg3 = xp[(size_t)(1536 + j) * 32 + nn];
        }
        f32x4 acc;
#pragma unroll
        for (int r = 0; r < 4; ++r) acc[r] = 0.0f;
        {   // h0(t) half first (no barrier dependency): ktiles 16..31
            const us_t* h0s = h0b + (size_t)t * 16384;
            uint4 a0 = ((const uint4*)h0s)[tid];
            uint4 a1 = ((const uint4*)(h0s + 8192))[tid];
            ((uint4*)Ax0)[tid] = a0;
            __syncthreads();
            ((uint4*)Ax1)[tid] = a1;
            compute1(acc, Ax0, 16, Mt, kq, l16, quad, lds_w);
            __syncthreads();
            compute1(acc, Ax1, 24, Mt, kq, l16, quad, lds_w);
        }
        wait_all(flg, base, tid);                  // attc(t) (normalized) ready
        {
            const float* cts = ctx + (size_t)t * 16384;
            us_t* atbt = atb + (size_t)t * 16384;
            // issue both chunk loads up front
            float4 a0 = *(const float4*)(cts + (size_t)tid * 8);
            float4 c0 = *(const float4*)(cts + (size_t)tid * 8 + 4);
            float4 a1 = *(const float4*)(cts + (size_t)(1024 + tid) * 8);
            float4 c1 = *(const float4*)(cts + (size_t)(1024 + tid) * 8 + 4);
            uint4 pk0 = cvt_pk8(a0, c0);
            *(uint4*)(Ax0 + (size_t)tid * 8) = pk0;
            if ((tid >> 3) == b) *(uint4*)(atbt + (size_t)tid * 8) = pk0;
            __syncthreads();
            uint4 pk1 = cvt_pk8(a1, c1);
            *(uint4*)(Ax1 + (size_t)tid * 8) = pk1;
            {
                int gs = 1024 + tid;
                if ((gs >> 3) == b) *(uint4*)(atbt + (size_t)gs * 8) = pk1;
            }
            compute1(acc, Ax0, 0, Mt, kq, l16, quad, lds_w);
            __syncthreads();
            compute1(acc, Ax1, 8, Mt, kq, l16, quad, lds_w);
        }
        tail_pub(acc, 0, xg0, xg1, xg2, xg3, c0r,
                 (u32*)(h0b + (size_t)(t + 1) * 16384), nullptr, b, tid, red_s, gv_s);
        arrive(flg, b, tid, base + 1);
        // ============ P2: LSTM1, X = [h0(t+1) k0..511 | h1(t) k512..1023] ============
#pragma unroll
        for (int r = 0; r < 4; ++r) acc[r] = 0.0f;
        {   // h1(t) half first: ktiles 16..31
            const us_t* h1s = h1b + (size_t)t * 16384;
            uint4 a0 = ((const uint4*)h1s)[tid];
            uint4 a1 = ((const uint4*)(h1s + 8192))[tid];
            ((uint4*)Ax0)[tid] = a0;
            __syncthreads();
            ((uint4*)Ax1)[tid] = a1;
            compute1(acc, Ax0, 16, Mt, kq, l16, quad, lds_w);
            __syncthreads();
            compute1(acc, Ax1, 24, Mt, kq, l16, quad, lds_w);
        }
        wait_all(flg, base + 1, tid);
        {
            const us_t* h0n = h0b + (size_t)(t + 1) * 16384;
            uint4 a0 = ((const uint4*)h0n)[tid];
            uint4 a1 = ((const uint4*)(h0n + 8192))[tid];
            ((uint4*)Ax0)[tid] = a0;
            __syncthreads();
            ((uint4*)Ax1)[tid] = a1;
            compute1(acc, Ax0, 0, Mt, kq, l16, quad, lds_w);
            __syncthreads();
            compute1(acc, Ax1, 8, Mt, kq, l16, quad, lds_w);
        }
        tail_pub(acc, 8, bs0, bs1, bs2, bs3, c1r,
                 (u32*)(h1b + (size_t)(t + 1) * 16384),
                 h1T32 + (size_t)(t + 1) * 8320, b, tid, red_s, gv_s);
        arrive(flg, b, tid, base + 2);
        // ============ ATTN: 8 chunk blocks/sample (XCD-local), cv overlaps mz mini-sync ============
        wait_all(flg, base + 2, tid);
        {
            float* h_l = (float*)Ax0;      // [16][33] = 528 f padded h
            float* scp = h_l + 528;        // [16][66] = 1056 f
            float* p_l = h_l + 1584;       // 64 f
            float* aux = h_l + 1648;       // 2 f
            if (tid < 256) {
                u32 hv = h1T32[(size_t)(t + 1) * 8320 + an * 260 + tid];
                int idx = tid * 2;
                int kp = idx >> 5, off = idx & 31;
                h_l[kp * 33 + off]     = bfl(hv);
                h_l[kp * 33 + off + 1] = bfh(hv);
            }
            __syncthreads();
            {
                int ti = tid >> 4, kp = tid & 15;
                const us_t* er = lds_e + (size_t)ti * 552 + (kp >> 2) * 136 + (kp & 3) * 32;
                const float* hr = h_l + kp * 33;
                float s = 0.0f;
#pragma unroll
                for (int k8 = 0; k8 < 4; ++k8) {
                    uint4 u = *(const uint4*)(er + k8 * 8);
                    const float* h8 = hr + k8 * 8;
                    s += bfl(u.x) * h8[0] + bfh(u.x) * h8[1]
                       + bfl(u.y) * h8[2] + bfh(u.y) * h8[3]
                       + bfl(u.z) * h8[4] + bfh(u.z) * h8[5]
                       + bfl(u.w) * h8[6] + bfh(u.w) * h8[7];
                }
                scp[kp * 66 + ti] = s;
            }
            __syncthreads();
            if (tid < 64) {
                float sc = 0.0f;
#pragma unroll
                for (int kp = 0; kp < 16; ++kp) sc += scp[kp * 66 + tid];
                float m = sc;
                for (int o = 32; o; o >>= 1) m = fmaxf(m, __shfl_xor(m, o));
                float e = __expf(sc - m);
                float z = e;
                for (int o = 32; o; o >>= 1) z += __shfl_xor(z, o);
                p_l[tid] = e;
                if (tid == 0) {
                    aux[0] = m;      // own chunk max
                    u64 pk = ((u64)__float_as_uint(m) << 32) | (u64)__float_as_uint(z);
                    __hip_atomic_store(mz + ((size_t)(t + 1) * 256 + an * 8 + ac), pk,
                                       __ATOMIC_RELAXED, __HIP_MEMORY_SCOPE_AGENT);
                }
            }
            __syncthreads();
            // unnormalized ctx contribution FIRST (overlaps sibling mz publishes)
            int d = tid >> 1, half = tid & 1;
            const us_t* eb = lds_e + (d >> 7) * 136 + (d & 127);
            float cv = 0.0f;
#pragma unroll 8
            for (int i = 0; i < 32; ++i) {
                int ti2 = half * 32 + i;
                cv += p_l[ti2] * bfl((u32)eb[(size_t)ti2 * 552]);
            }
            // mini-sync among the 8 chunk blocks of this sample -> global (M, Z)
            if (tid < 8) {
                u64 v;
                for (;;) {
                    v = __hip_atomic_load(mz + ((size_t)(t + 1) * 256 + an * 8 + tid),
                                          __ATOMIC_RELAXED, __HIP_MEMORY_SCOPE_AGENT);
                    if ((u32)v != 0u) break;
                    __builtin_amdgcn_s_sleep(1);
                }
                float mi = __uint_as_float((u32)(v >> 32));
                float zi = __uint_as_float((u32)v);
#pragma unroll
                for (int o = 1; o < 8; o <<= 1) {
                    float mo = __shfl_xor(mi, o);
                    float zo = __shfl_xor(zi, o);
                    float Mn = fmaxf(mi, mo);
                    zi = zi * __expf(mi - Mn) + zo * __expf(mo - Mn);
                    mi = Mn;
                }
                if (tid == 0)
                    aux[1] = __expf(aux[0] - mi) / zi;   // normalized scale for this chunk
            }
            __syncthreads();
            float scl = aux[1];
            float ov = __shfl_xor(cv, 1);
            if (half == 0) {
                int gs = (d >> 3) * 32 + an;
                float* dst = ctx + (size_t)(t + 1) * 16384 + (size_t)gs * 8 + (d & 7);
                __hip_atomic_fetch_add(dst, (cv + ov) * scl,
                                       __ATOMIC_RELAXED, __HIP_MEMORY_SCOPE_AGENT);
            }
        }
        arrive(flg, b, tid, base + 3);
    }
    // tail: materialize bf16 attc(129) for k_mlp (ctx already normalized)
    wait_all(flg, 3u * T_STEPS, tid);
    if (tid < 8) {
        int gs = b * 8 + tid;
        const float* s = ctx + (size_t)129 * 16384 + (size_t)gs * 8;
        float4 a = *(const float4*)s;
        float4 c = *(const float4*)(s + 4);
        uint4 pk = cvt_pk8(a, c);
        *(uint4*)(atb + (size_t)129 * 16384 + (size_t)gs * 8) = pk;
    }
}

// ---------------- MLP hidden GEMM (granule-major bf16 in, bf16 out) ----------------
__global__ __launch_bounds__(256) void k_mlp(const us_t* __restrict__ h1b,
                                             const us_t* __restrict__ atb,
                                             const float* __restrict__ W1,
                                             const float* __restrict__ b1,
                                             us_t* __restrict__ hidb) {
    __shared__ __align__(16) float At[32 * 33];
    __shared__ __align__(16) float Bt[32 * 68];
    const int t = blockIdx.x, j0 = blockIdx.y * 64, tid = threadIdx.x;
    const int ty = tid >> 4, tx = tid & 15;
    float acc[8];
#pragma unroll
    for (int i = 0; i < 8; ++i) acc[i] = 0.0f;
    for (int k0 = 0; k0 < 1024; k0 += 32) {
        const us_t* src = (k0 < 512) ? (h1b + (size_t)(t + 1) * 16384 + (size_t)k0 * 32)
                                     : (atb + (size_t)t * 16384 + (size_t)(k0 - 512) * 32);
        __syncthreads();
        if (tid < 128) {   // 32k x 32n tile = 4 granule-rows
            int g8l = tid >> 5, n = tid & 31;
            uint4 v = *(const uint4*)(src + ((size_t)g8l * 32 + n) * 8);
            float* a = At + (size_t)(g8l * 8) * 33 + n;
            a[0]   = bfl(v.x); a[33]  = bfh(v.x);
            a[66]  = bfl(v.y); a[99]  = bfh(v.y);
            a[132] = bfl(v.z); a[165] = bfh(v.z);
            a[198] = bfl(v.w); a[231] = bfh(v.w);
        }
        {
#pragma unroll
            for (int i2 = 0; i2 < 2; ++i2) {
                int f = tid + 256 * i2;
                int j = f >> 3, kb = f & 7;
                float4 wv = *(const float4*)(W1 + (size_t)(j0 + j) * 1024 + k0 + kb * 4);
                Bt[(kb * 4 + 0) * 68 + j] = wv.x;
                Bt[(kb * 4 + 1) * 68 + j] = wv.y;
                Bt[(kb * 4 + 2) * 68 + j] = wv.z;
                Bt[(kb * 4 + 3) * 68 + j] = wv.w;
            }
        }
        __syncthreads();
#pragma unroll
        for (int kk = 0; kk < 32; ++kk) {
            float a0 = At[kk * 33 + ty], a1 = At[kk * 33 + ty + 16];
            float4 b4 = *(const float4*)&Bt[kk * 68 + tx * 4];
            acc[0] += a0 * b4.x; acc[1] += a0 * b4.y; acc[2] += a0 * b4.z; acc[3] += a0 * b4.w;
            acc[4] += a1 * b4.x; acc[5] += a1 * b4.y; acc[6] += a1 * b4.z; acc[7] += a1 * b4.w;
        }
    }
    int j = j0 + tx * 4;
    float4 bv = *(const float4*)(b1 + j);
    int r0 = t * 32;
    ushort4 p0 = {f2b(tanhf(acc[0] + bv.x)), f2b(tanhf(acc[1] + bv.y)),
                  f2b(tanhf(acc[2] + bv.z)), f2b(tanhf(acc[3] + bv.w))};
    ushort4 p1 = {f2b(tanhf(acc[4] + bv.x)), f2b(tanhf(acc[5] + bv.y)),
                  f2b(tanhf(acc[6] + bv.z)), f2b(tanhf(acc[7] + bv.w))};
    *(ushort4*)(hidb + (size_t)(r0 + ty) * 512 + j) = p0;
    *(ushort4*)(hidb + (size_t)(r0 + ty + 16) * 512 + j) = p1;
}

// ---------------- MFMA logits + chunk logsumexp (unchanged) ----------------
__global__ __launch_bounds__(256) void k_ce(const us_t* __restrict__ hidb,
                                            const us_t* __restrict__ W2p,
                                            const float* __restrict__ b2,
                                            const int* __restrict__ padded,
                                            float* __restrict__ cpm, float* __restrict__ cps,
                                            float* __restrict__ tgt) {
    __shared__ __align__(16) us_t Ash[32 * 520];
    __shared__ __align__(16) float lg[256 * 33];
    __shared__ float mred[8 * 32];
    __shared__ float Mf[32];
    __shared__ float sred[8 * 32];
    const int t = blockIdx.x, vc = blockIdx.y, tid = threadIdx.x;
    {
        const uint4* src = (const uint4*)(hidb + (size_t)t * 32 * 512);
#pragma unroll
        for (int i = 0; i < 8; ++i) {
            int f = tid + i * 256;
            uint4 v = src[f];
            *(uint4*)(Ash + (size_t)(f >> 6) * 520 + (f & 63) * 8) = v;
        }
    }
    __syncthreads();
    const int w = tid >> 6, lane = tid & 63;
    const int quad = lane >> 4, l16 = lane & 15;
    f32x4 acc[2][4];
#pragma unroll
    for (int mt = 0; mt < 2; ++mt)
#pragma unroll
        for (int nt = 0; nt < 4; ++nt)
#pragma unroll
            for (int r = 0; r < 4; ++r) acc[mt][nt][r] = 0.0f;
    const int vbase = vc * 256 + w * 64;
    for (int ks = 0; ks < 16; ++ks) {
        bf16x8 a0 = *(const bf16x8*)(Ash + (size_t)(l16)      * 520 + ks * 32 + quad * 8);
        bf16x8 a1 = *(const bf16x8*)(Ash + (size_t)(16 + l16) * 520 + ks * 32 + quad * 8);
        const us_t* bp = W2p + ((size_t)(ks * 4 + quad) * 4096 + vbase + l16) * 8;
#pragma unroll
        for (int nt = 0; nt < 4; ++nt) {
            bf16x8 bb = *(const bf16x8*)(bp + nt * 128);
            acc[0][nt] = __builtin_amdgcn_mfma_f32_16x16x32_bf16(a0, bb, acc[0][nt], 0, 0, 0);
            acc[1][nt] = __builtin_amdgcn_mfma_f32_16x16x32_bf16(a1, bb, acc[1][nt], 0, 0, 0);
        }
    }
#pragma unroll
    for (int nt = 0; nt < 4; ++nt) {
        int vloc = w * 64 + nt * 16 + l16;
        int vglob = vc * 256 + vloc;
        float bias = (vglob < V) ? b2[vglob] : -1e30f;
#pragma unroll
        for (int mt = 0; mt < 2; ++mt)
#pragma unroll
            for (int r = 0; r < 4; ++r)
                lg[vloc * 33 + mt * 16 + quad * 4 + r] = acc[mt][nt][r] + bias;
    }
    __syncthreads();
    {
        int n = tid & 31, c = tid >> 5;
        float m = -1e30f;
        for (int i = 0; i < 32; ++i) m = fmaxf(m, lg[(c * 32 + i) * 33 + n]);
        mred[c * 32 + n] = m;
    }
    __syncthreads();
    if (tid < 32) {
        float M = mred[tid];
#pragma unroll
        for (int c = 1; c < 8; ++c) M = fmaxf(M, mred[c * 32 + tid]);
        Mf[tid] = M;
    }
    __syncthreads();
    {
        int n = tid & 31, c = tid >> 5;
        float M = Mf[n], s = 0.0f;
        for (int i = 0; i < 32; ++i) s += __expf(lg[(c * 32 + i) * 33 + n] - M);
        sred[c * 32 + n] = s;
    }
    __syncthreads();
    if (tid < 32) {
        int n = tid;
        float S = 0.0f;
#pragma unroll
        for (int c = 0; c < 8; ++c) S += sred[c * 32 + n];
        int r = t * 32 + n;
        cpm[(size_t)r * 16 + vc] = Mf[n];
        cps[(size_t)r * 16 + vc] = S;
        int vstar = (t < 128) ? padded[n * 128 + t] : 2;
        int vl = vstar - vc * 256;
        if (vl >= 0 && vl < 256) tgt[r] = lg[vl * 33 + n];
    }
}

// ---------------- final combine + CE reduction (unchanged) ----------------
__global__ __launch_bounds__(256) void k_final(const float* __restrict__ cpm,
                                               const float* __restrict__ cps,
                                               const float* __restrict__ tgt,
                                               float* __restrict__ out) {
    __shared__ float red[256];
    float local = 0.0f;
    for (int r = threadIdx.x; r < 4128; r += 256) {
        float M = -1e30f;
#pragma unroll
        for (int c = 0; c < 16; ++c) M = fmaxf(M, cpm[(size_t)r * 16 + c]);
        float S = 0.0f;
#pragma unroll
        for (int c = 0; c < 16; ++c) S += cps[(size_t)r * 16 + c] * __expf(cpm[(size_t)r * 16 + c] - M);
        local += (M + logf(S)) - tgt[r];
    }
    red[threadIdx.x] = local;
    __syncthreads();
    for (int o = 128; o; o >>= 1) {
        if (threadIdx.x < o) red[threadIdx.x] += red[threadIdx.x + o];
        __syncthreads();
    }
    if (threadIdx.x == 0) out[0] = red[0] * (128.0f / 4128.0f);
}

extern "C" void kernel_launch(void* const* d_in, const int* in_sizes, int n_in,
                              void* d_out, int out_size, void* d_ws, size_t ws_size,
                              hipStream_t stream) {
    const int*   padded = (const int*)d_in[0];
    const float* enc    = (const float*)d_in[1];
    const float* emb    = (const float*)d_in[2];
    const float* W_ih0  = (const float*)d_in[3];
    const float* b_ih0  = (const float*)d_in[4];
    const float* W_hh0  = (const float*)d_in[5];
    const float* b_hh0  = (const float*)d_in[6];
    const float* W_ih1  = (const float*)d_in[7];
    const float* b_ih1  = (const float*)d_in[8];
    const float* W_hh1  = (const float*)d_in[9];
    const float* b_hh1  = (const float*)d_in[10];
    const float* W1     = (const float*)d_in[11];
    const float* b1     = (const float*)d_in[12];
    const float* W2     = (const float*)d_in[13];
    const float* b2     = (const float*)d_in[14];
    float* ws  = (float*)d_ws;
    float* out = (float*)d_out;

    hipLaunchKernelGGL(k_init, dim3(640), dim3(256), 0, stream, ws);
    hipLaunchKernelGGL(k_packWq, dim3(16384), dim3(256), 0, stream,
                       W_ih0, W_hh0, W_ih1, W_hh1, (us_t*)(ws + OFF_WQ));
    hipLaunchKernelGGL(k_packW2, dim3(8192), dim3(256), 0, stream,
                       W2, (us_t*)(ws + OFF_W2P));
    hipLaunchKernelGGL(k_xpre, dim3(129, 32), dim3(256), 0, stream,
                       padded, emb, W_ih0, b_ih0, b_hh0, ws + OFF_XPRE);
    {
        float* ws_a = ws;
        const float* enc_a = enc;
        const float* bia = b_ih1;
        const float* bib = b_hh1;
        void* args[] = {(void*)&ws_a, (void*)&enc_a, (void*)&bia, (void*)&bib};
        hipLaunchCooperativeKernel((void*)k_seq, dim3(256), dim3(1024), args, 0, stream);
    }
    hipLaunchKernelGGL(k_mlp, dim3(129, 8), dim3(256), 0, stream,
                       (const us_t*)(ws + OFF_H1B), (const us_t*)(ws + OFF_ATB), W1, b1,
                       (us_t*)(ws + OFF_HID));
    hipLaunchKernelGGL(k_ce, dim3(129, 16), dim3(256), 0, stream,
                       (const us_t*)(ws + OFF_HID), (const us_t*)(ws + OFF_W2P), b2, padded,
                       ws + OFF_CPM, ws + OFF_CPS, ws + OFF_TGT);
    hipLaunchKernelGGL(k_final, dim3(1), dim3(256), 0, stream,
                       ws + OFF_CPM, ws + OFF_CPS, ws + OFF_TGT, out);
}